// Round 13
// baseline (2402.456 us; speedup 1.0000x reference)
//
#include <hip/hip_runtime.h>
#include <hip/hip_bf16.h>
#include <math.h>

#define LN 4
#define B_ 8
#define D_ 2048
#define DI 4096
#define N_ 128
#define H_ 64
#define P_ 64
#define K_ 4
#define M_ 8
#define V_ 50288
#define CCH (DI + 2*N_)           // 4352
#define DOUT (2*DI + 2*N_ + H_)   // 8512
#define EPSF 1e-5f
#define KT_IN 32                  // in_proj k-tiles (k0=64)
#define KT_OUT 128                // out_proj k-tiles (k0=32)
#define GT 1024                   // k_tail grid (co-resident: 4 blocks/CU x 256 CU)

typedef float f32x4 __attribute__((ext_vector_type(4)));

__device__ inline float wave_sum(float v) {
  #pragma unroll
  for (int off = 32; off > 0; off >>= 1) v += __shfl_xor(v, off, 64);
  return v;
}

// Fold-reduce 8 per-lane accumulators: lane l gets full 64-lane sum of a[l&7].
__device__ inline float fold_reduce8(const float a[8], int lane) {
  float t0[4];
  #pragma unroll
  for (int r = 0; r < 4; ++r) {
    float keep = (lane & 1) ? a[2*r+1] : a[2*r];
    float send = (lane & 1) ? a[2*r]   : a[2*r+1];
    t0[r] = keep + __shfl_xor(send, 1, 64);
  }
  float t1[2];
  #pragma unroll
  for (int r = 0; r < 2; ++r) {
    float keep = (lane & 2) ? t0[2*r+1] : t0[2*r];
    float send = (lane & 2) ? t0[2*r]   : t0[2*r+1];
    t1[r] = keep + __shfl_xor(send, 2, 64);
  }
  float keep = (lane & 4) ? t1[1] : t1[0];
  float send = (lane & 4) ? t1[0] : t1[1];
  float u = keep + __shfl_xor(send, 4, 64);
  u += __shfl_xor(u, 8, 64);
  u += __shfl_xor(u, 16, 64);
  u += __shfl_xor(u, 32, 64);
  return u;
}

// Grid-wide barrier: monotonic counter, device-scope atomics (all GT blocks
// co-resident by __launch_bounds__ occupancy guarantee).
__device__ inline void grid_bar(unsigned* cnt, unsigned target) {
  __syncthreads();
  if (threadIdx.x == 0) {
    __threadfence();
    __hip_atomic_fetch_add(cnt, 1u, __ATOMIC_RELEASE, __HIP_MEMORY_SCOPE_AGENT);
    while (__hip_atomic_load(cnt, __ATOMIC_ACQUIRE, __HIP_MEMORY_SCOPE_AGENT) < target)
      __builtin_amdgcn_s_sleep(8);
  }
  __syncthreads();
}

__global__ void k_init(unsigned* __restrict__ cnt) {
  if (threadIdx.x == 0) *cnt = 0u;
}

// ------ in_proj stage 1, LAYER 0: embed-gather + in-block rmsnorm prologue ---
__global__ __launch_bounds__(256)
void k_inproj1_first(const int* __restrict__ ids, const float* __restrict__ emb,
                     const float* __restrict__ lnw, const float* __restrict__ W,
                     float* __restrict__ pin) {
  __shared__ float xs[8][64];
  __shared__ float sred[4][8];
  int tid = threadIdx.x, lane = tid & 63, wid = tid >> 6;
  int jt = blockIdx.x % 9, kt = blockIdx.x / 9;
  int k0 = kt * 64;
  float ssq[8];
  #pragma unroll
  for (int r = 0; r < 8; ++r) {
    const float* row = emb + (size_t)ids[r] * D_;
    f32x4 a = *reinterpret_cast<const f32x4*>(row + tid * 8);
    f32x4 c = *reinterpret_cast<const f32x4*>(row + tid * 8 + 4);
    ssq[r] = a[0]*a[0] + a[1]*a[1] + a[2]*a[2] + a[3]*a[3]
           + c[0]*c[0] + c[1]*c[1] + c[2]*c[2] + c[3]*c[3];
  }
  #pragma unroll
  for (int r = 0; r < 8; ++r) {
    float wsum = wave_sum(ssq[r]);
    if (lane == 0) sred[wid][r] = wsum;
  }
  __syncthreads();
  for (int i = tid; i < 8 * 64; i += 256) {
    int r = i >> 6, kk = i & 63;
    const float* row = emb + (size_t)ids[r] * D_;
    float tot = sred[0][r] + sred[1][r] + sred[2][r] + sred[3][r];
    float scale = rsqrtf(tot / (float)D_ + EPSF);
    xs[r][kk] = row[k0 + kk] * scale * lnw[k0 + kk];
  }
  __syncthreads();
  int j = jt * 1024 + tid * 4;
  if (j >= DOUT) return;
  f32x4 acc[8];
  #pragma unroll
  for (int r = 0; r < 8; ++r) acc[r] = (f32x4)0.f;
  const float* Wp = W + (size_t)k0 * DOUT + j;
  for (int kk = 0; kk < 64; ++kk) {
    f32x4 w4 = __builtin_nontemporal_load(
        reinterpret_cast<const f32x4*>(Wp + (size_t)kk * DOUT));
    #pragma unroll
    for (int r = 0; r < 8; ++r) acc[r] += w4 * xs[r][kk];
  }
  #pragma unroll
  for (int r = 0; r < 8; ++r)
    *reinterpret_cast<f32x4*>(&pin[((size_t)kt * 8 + r) * DOUT + j]) = acc[r];
}

// ------ in_proj stage 1, layers 1-3: 288 blocks, norm via ssq_in -------------
__global__ __launch_bounds__(256)
void k_inproj1(const float* __restrict__ res, const float* __restrict__ ssq_in,
               const float* __restrict__ lnw, const float* __restrict__ W,
               float* __restrict__ pin) {
  __shared__ float xs[8][64];
  int tid = threadIdx.x;
  int jt = blockIdx.x % 9, kt = blockIdx.x / 9;
  int k0 = kt * 64;
  for (int i = tid; i < 8 * 64; i += 256) {
    int r = i >> 6, kk = i & 63;
    float scale = rsqrtf(ssq_in[r] / (float)D_ + EPSF);
    xs[r][kk] = res[r * D_ + k0 + kk] * scale * lnw[k0 + kk];
  }
  __syncthreads();
  int j = jt * 1024 + tid * 4;
  if (j >= DOUT) return;
  f32x4 acc[8];
  #pragma unroll
  for (int r = 0; r < 8; ++r) acc[r] = (f32x4)0.f;
  const float* Wp = W + (size_t)k0 * DOUT + j;
  for (int kk = 0; kk < 64; ++kk) {
    f32x4 w4 = __builtin_nontemporal_load(
        reinterpret_cast<const f32x4*>(Wp + (size_t)kk * DOUT));
    #pragma unroll
    for (int r = 0; r < 8; ++r) acc[r] += w4 * xs[r][kk];
  }
  #pragma unroll
  for (int r = 0; r < 8; ++r)
    *reinterpret_cast<f32x4*>(&pin[((size_t)kt * 8 + r) * DOUT + j]) = acc[r];
}

// ------ fused layer tail: {inproj2+conv | state+gnorm-ssq | outproj1 | outproj2}
// 3 in-kernel grid barriers replace 4 kernel launches.
__global__ __launch_bounds__(256, 4)
void k_tail(const float* __restrict__ pin,
            const float* __restrict__ conv_state, const float* __restrict__ conv_w,
            const float* __restrict__ conv_b, const float* __restrict__ A_log,
            const float* __restrict__ dt_bias, const float* __restrict__ W_mc,
            const float* __restrict__ Dp_, const float* __restrict__ mnw,
            const float* __restrict__ Wout,
            const int* __restrict__ ids, const float* __restrict__ emb,
            const float* __restrict__ ssm, const float* __restrict__ cached,
            float* __restrict__ zx, float* __restrict__ xbc,
            float* __restrict__ dts, float* __restrict__ dav,
            float* __restrict__ wmc, float* __restrict__ y,
            float* __restrict__ pout, float* __restrict__ res,
            float* __restrict__ ssq_in, float* __restrict__ gssq,
            unsigned* __restrict__ cnt, unsigned base) {
  __shared__ float xs[8][32];     // phase D staging
  __shared__ f32x4 red4[256];     // phase E reduce
  __shared__ float gred[32];      // phase B gnorm partials
  int tid = threadIdx.x, bid = blockIdx.x;

  // ---------- Phase A: reduce pin -> zx, conv+silu, dt/dA, softmax(W_mc) ----
  {
    if (bid == 0) {
      if (tid < 8) ssq_in[tid] = 0.f;
      else if (tid < 16) gssq[tid - 8] = 0.f;
    }
    const int TOT4 = B_ * DOUT / 4;   // 17024
    int t = bid * 256 + tid;
    if (t < TOT4) {
      f32x4 s = (f32x4)0.f;
      const f32x4* p4 = reinterpret_cast<const f32x4*>(pin) + t;
      #pragma unroll 8
      for (int kt = 0; kt < KT_IN; ++kt) s += p4[(size_t)kt * TOT4];
      reinterpret_cast<f32x4*>(zx)[t] = s;
      int c4 = t * 4;
      int b = c4 / DOUT;
      int c = c4 - b * DOUT;
      #pragma unroll
      for (int e = 0; e < 4; ++e) {
        int ce = c + e;
        if (ce >= DI && ce < DI + CCH) {
          int cc = ce - DI;
          f32x4 cs4 = *reinterpret_cast<const f32x4*>(conv_state + ((size_t)b * CCH + cc) * K_);
          f32x4 cw4 = *reinterpret_cast<const f32x4*>(conv_w + (size_t)cc * K_);
          float v = cs4[1] * cw4[0] + cs4[2] * cw4[1] + cs4[3] * cw4[2]
                  + s[e] * cw4[3] + conv_b[cc];
          xbc[b * CCH + cc] = v / (1.f + expf(-v));   // silu
        } else if (ce >= DI + CCH) {
          int h = ce - DI - CCH;
          float x = s[e] + dt_bias[h];
          float sp = (x > 20.f) ? x : log1pf(expf(x));  // softplus
          dts[b * 64 + h] = sp;
          dav[b * 64 + h] = expf(-expf(A_log[h]) * sp);
        }
      }
      if (t == 0) {
        float mx = -1e30f;
        for (int i = 0; i < M_ + 1; ++i) mx = fmaxf(mx, W_mc[i]);
        float e2[M_ + 1], sum = 0.f;
        for (int i = 0; i < M_ + 1; ++i) { e2[i] = expf(W_mc[i] - mx); sum += e2[i]; }
        for (int i = 0; i < M_ + 1; ++i) wmc[i] = e2[i] / sum;
      }
    }
  }
  grid_bar(cnt, base + GT);

  // ---------- Phase B: state update + y + gated-norm ssq accumulation -------
  {
    int lane = tid & 63, hf = lane >> 5, il = lane & 31;
    int w = bid * 4 + (tid >> 6);
    int it0 = w * 4;                 // 4 consecutive items; b uniform per block
    int b = it0 >> 11;
    float w8 = wmc[8];
    const f32x4* xb4 = reinterpret_cast<const f32x4*>(xbc);
    f32x4 B4 = xb4[b * (CCH / 4) + DI / 4 + il];
    f32x4 C4 = xb4[b * (CCH / 4) + DI / 4 + N_ / 4 + il];
    #pragma unroll
    for (int q = 0; q < 4; ++q) {
      int it = it0 + q;
      int h = (it >> 5) & 63;
      int pp = it & 31;
      int p = pp * 2 + hf;
      float xv  = xbc[b * CCH + h * 64 + p];
      float dtv = dts[b * 64 + h];
      float da  = dav[b * 64 + h];
      const f32x4* sp4 = reinterpret_cast<const f32x4*>(ssm) +
                         ((size_t)((b * H_ + h) * P_ + p)) * (N_ / 4) + il;
      const f32x4* cp4 = reinterpret_cast<const f32x4*>(cached) +
                         ((size_t)(((b * M_) * H_ + h) * P_ + p)) * (N_ / 4) + il;
      f32x4 s4 = __builtin_nontemporal_load(sp4);
      f32x4 f4 = (s4 * da + B4 * (dtv * xv)) * w8;
      #pragma unroll
      for (int m = 0; m < 8; ++m) {
        f32x4 c4 = __builtin_nontemporal_load(cp4 + (size_t)m * (H_ * P_ * N_ / 4));
        f4 += c4 * wmc[m];
      }
      f4 *= C4;
      float acc = f4[0] + f4[1] + f4[2] + f4[3];
      #pragma unroll
      for (int off = 1; off < 32; off <<= 1) acc += __shfl_xor(acc, off, 64);
      if (il == 0) {
        float yv = acc + Dp_[h] * xv;
        int d = h * 64 + p;
        y[b * DI + d] = yv;
        float z = zx[b * DOUT + d];
        float v = yv * (z / (1.f + expf(-z)));
        gred[(tid >> 6) * 8 + q * 2 + hf] = v * v;
      }
    }
    __syncthreads();
    if (tid == 0) {
      float g = 0.f;
      #pragma unroll
      for (int i = 0; i < 32; ++i) g += gred[i];
      atomicAdd(&gssq[bid >> 7], g);
    }
  }
  grid_bar(cnt, base + 2 * GT);

  // ---------- Phase D: outproj1 (blocks 0..255), gated-norm applied inline --
  if (bid < 256) {
    int jt = bid & 1, kt = bid >> 1;
    int k0 = kt * 32;
    {
      int r = tid >> 5, kk = tid & 31;
      float scale = rsqrtf(gssq[r] / (float)DI + EPSF);
      float z = zx[r * DOUT + k0 + kk];
      float g = z / (1.f + expf(-z));
      xs[r][kk] = y[r * DI + k0 + kk] * g * scale * mnw[k0 + kk];
    }
    __syncthreads();
    int j = jt * 1024 + tid * 4;
    f32x4 acc[8];
    #pragma unroll
    for (int r = 0; r < 8; ++r) acc[r] = (f32x4)0.f;
    const float* Wp = Wout + (size_t)k0 * D_ + j;
    for (int kk = 0; kk < 32; ++kk) {
      f32x4 w4 = __builtin_nontemporal_load(
          reinterpret_cast<const f32x4*>(Wp + (size_t)kk * D_));
      #pragma unroll
      for (int r = 0; r < 8; ++r) acc[r] += w4 * xs[r][kk];
    }
    #pragma unroll
    for (int r = 0; r < 8; ++r)
      *reinterpret_cast<f32x4*>(&pout[((size_t)kt * 8 + r) * D_ + j]) = acc[r];
  }
  grid_bar(cnt, base + 3 * GT);

  // ---------- Phase E: outproj2 (blocks 0..63): res update + next ssq_in ----
  if (bid < 64) {
    const int TOT4 = B_ * D_ / 4;   // 4096
    int pos = bid * 64 + (tid & 63);
    int kq = tid >> 6;
    const f32x4* p4 = reinterpret_cast<const f32x4*>(pout) + pos;
    f32x4 s = (f32x4)0.f;
    #pragma unroll 8
    for (int k = 0; k < 32; ++k)
      s += p4[(size_t)(kq * 32 + k) * TOT4];
    red4[tid] = s;
    __syncthreads();
    if (tid < 64) {
      f32x4 tot = red4[tid] + red4[tid + 64] + red4[tid + 128] + red4[tid + 192];
      f32x4* r4 = reinterpret_cast<f32x4*>(res);
      f32x4 nv;
      if (ids) {
        int b = pos >> 9, d4 = pos & 511;
        f32x4 bse = reinterpret_cast<const f32x4*>(emb)[(size_t)ids[b] * (D_ / 4) + d4];
        nv = bse + tot;
      } else {
        nv = r4[pos] + tot;
      }
      r4[pos] = nv;
      float ps = nv[0]*nv[0] + nv[1]*nv[1] + nv[2]*nv[2] + nv[3]*nv[3];
      ps = wave_sum(ps);
      if (tid == 0) atomicAdd(&ssq_in[pos >> 9], ps);
    }
  }
}

// ---------------- logits: wave-per-row, split-D (SL=4), FUSED final norm -----
#define SL_ 4
#define KS_ (D_ / SL_)            // 512
#define NVB16 (V_ / 16)           // 3143 (exact)
__global__ __launch_bounds__(256)
void k_logits(const float* __restrict__ res, const float* __restrict__ ssq_in,
              const float* __restrict__ nfw, const float* __restrict__ emb,
              float* __restrict__ pl) {
  __shared__ f32x4 xs[8][KS_ / 4];   // 16 KB -> 8 blocks/CU, 32 waves/CU
  int s = blockIdx.x & 3, vb = blockIdx.x >> 2;
  const f32x4* res4 = reinterpret_cast<const f32x4*>(res);
  const f32x4* nfw4 = reinterpret_cast<const f32x4*>(nfw);
  for (int i = threadIdx.x; i < 8 * (KS_ / 4); i += 256) {
    int r = i >> 7, q = i & 127;
    float scale = rsqrtf(ssq_in[r] / (float)D_ + EPSF);
    xs[r][q] = res4[r * (D_ / 4) + s * (KS_ / 4) + q] * scale
             * nfw4[s * (KS_ / 4) + q];
  }
  __syncthreads();
  int wid = threadIdx.x >> 6, lane = threadIdx.x & 63;
  int v0 = vb * 16 + wid * 4;
  const f32x4* e4 = reinterpret_cast<const f32x4*>(emb);
  #pragma unroll
  for (int vv = 0; vv < 4; ++vv) {
    int v = v0 + vv;
    const f32x4* ep = e4 + (size_t)v * (D_ / 4) + s * (KS_ / 4);
    float acc[8] = {0,0,0,0,0,0,0,0};
    #pragma unroll
    for (int st = 0; st < KS_ / 256; ++st) {
      int c = st * 64 + lane;
      f32x4 e = __builtin_nontemporal_load(ep + c);
      #pragma unroll
      for (int r = 0; r < 8; ++r) {
        f32x4 x = xs[r][c];
        acc[r] += e[0]*x[0] + e[1]*x[1] + e[2]*x[2] + e[3]*x[3];
      }
    }
    float u = fold_reduce8(acc, lane);
    if (lane < 8) pl[((size_t)s * 8 + lane) * V_ + v] = u;
  }
}

// ---------------- logits combine: out = sum of 4 slice partials --------------
__global__ __launch_bounds__(256)
void k_logits2(const float* __restrict__ pl, float* __restrict__ out) {
  int v = blockIdx.x * 256 + threadIdx.x;
  if (v >= V_) return;
  int r = blockIdx.y;
  float t = pl[(size_t)r * V_ + v]
          + pl[((size_t)8  + r) * V_ + v]
          + pl[((size_t)16 + r) * V_ + v]
          + pl[((size_t)24 + r) * V_ + v];
  out[(size_t)r * V_ + v] = t;
}

extern "C" void kernel_launch(void* const* d_in, const int* in_sizes, int n_in,
                              void* d_out, int out_size, void* d_ws, size_t ws_size,
                              hipStream_t stream) {
  const int*   ids    = (const int*)  d_in[0];
  const float* emb    = (const float*)d_in[1];
  const float* inW    = (const float*)d_in[2];
  const float* convW  = (const float*)d_in[3];
  const float* convB  = (const float*)d_in[4];
  const float* Alog   = (const float*)d_in[5];
  const float* dtB    = (const float*)d_in[6];
  const float* Dpar   = (const float*)d_in[7];
  const float* mnw    = (const float*)d_in[8];
  const float* outW   = (const float*)d_in[9];
  const float* lnw    = (const float*)d_in[10];
  const float* nfw    = (const float*)d_in[11];
  const float* Wmc    = (const float*)d_in[12];
  const float* convS  = (const float*)d_in[13];
  const float* ssmS   = (const float*)d_in[14];
  const float* cached = (const float*)d_in[15];
  float* out = (float*)d_out;
  float* ws  = (float*)d_ws;

  float* res   = ws;            // 16384 floats
  float* zx    = ws + 16384;    // 68096
  float* xbc   = ws + 84480;    // 34816
  float* dts   = ws + 119296;   // 512
  float* dav   = ws + 119808;   // 512
  float* wmc   = ws + 120320;   // 64
  float* ssqi  = ws + 120384;   // 64 (8 used)
  float* gssq  = ws + 120448;   // 64 (8 used)
  float* y     = ws + 120512;   // 32768
  float* pin   = ws + 153280;   // 32*8*8512 = 2179072
  float* pout  = ws + 2332352;  // 128*8*2048 = 2097152
  float* pl    = ws + 4429504;  // 4*8*50288 = 1609216
  unsigned* cnt = (unsigned*)(ws + 6038720);

  k_init<<<1, 64, 0, stream>>>(cnt);
  for (int l = 0; l < LN; ++l) {
    if (l == 0)
      k_inproj1_first<<<288, 256, 0, stream>>>(ids, emb, lnw, inW, pin);
    else
      k_inproj1<<<288, 256, 0, stream>>>(res, ssqi, lnw + (size_t)l * D_,
                                         inW + (size_t)l * D_ * DOUT, pin);
    k_tail<<<GT, 256, 0, stream>>>(pin,
        convS + (size_t)l * B_ * CCH * K_, convW + (size_t)l * CCH * K_,
        convB + (size_t)l * CCH, Alog + l * H_, dtB + l * H_, Wmc + l * (M_ + 1),
        Dpar + l * H_, mnw + (size_t)l * DI, outW + (size_t)l * DI * D_,
        (l == 0) ? ids : nullptr, emb,
        ssmS + (size_t)l * B_ * H_ * P_ * N_,
        cached + (size_t)l * B_ * M_ * H_ * P_ * N_,
        zx, xbc, dts, dav, wmc, y, pout, res, ssqi, gssq,
        cnt, (unsigned)(l * 3 * GT));
  }
  k_logits<<<NVB16 * SL_, 256, 0, stream>>>(res, ssqi, nfw, emb, pl);
  k_logits2<<<dim3((V_ + 255) / 256, 8), 256, 0, stream>>>(pl, out);
}

// Round 14
// 554.765 us; speedup vs baseline: 4.3306x; 4.3306x over previous
//
#include <hip/hip_runtime.h>
#include <hip/hip_bf16.h>
#include <math.h>

#define LN 4
#define B_ 8
#define D_ 2048
#define DI 4096
#define N_ 128
#define H_ 64
#define P_ 64
#define K_ 4
#define M_ 8
#define V_ 50288
#define CCH (DI + 2*N_)           // 4352
#define DOUT (2*DI + 2*N_ + H_)   // 8512
#define EPSF 1e-5f
#define KT_IN 32                  // in_proj k-tiles (k0=64)
#define KT_OUT 128                // out_proj k-tiles (k0=32)

typedef float f32x4 __attribute__((ext_vector_type(4)));

__device__ inline float wave_sum(float v) {
  #pragma unroll
  for (int off = 32; off > 0; off >>= 1) v += __shfl_xor(v, off, 64);
  return v;
}

// Fold-reduce 8 per-lane accumulators: lane l gets full 64-lane sum of a[l&7].
__device__ inline float fold_reduce8(const float a[8], int lane) {
  float t0[4];
  #pragma unroll
  for (int r = 0; r < 4; ++r) {
    float keep = (lane & 1) ? a[2*r+1] : a[2*r];
    float send = (lane & 1) ? a[2*r]   : a[2*r+1];
    t0[r] = keep + __shfl_xor(send, 1, 64);
  }
  float t1[2];
  #pragma unroll
  for (int r = 0; r < 2; ++r) {
    float keep = (lane & 2) ? t0[2*r+1] : t0[2*r];
    float send = (lane & 2) ? t0[2*r]   : t0[2*r+1];
    t1[r] = keep + __shfl_xor(send, 2, 64);
  }
  float keep = (lane & 4) ? t1[1] : t1[0];
  float send = (lane & 4) ? t1[0] : t1[1];
  float u = keep + __shfl_xor(send, 4, 64);
  u += __shfl_xor(u, 8, 64);
  u += __shfl_xor(u, 16, 64);
  u += __shfl_xor(u, 32, 64);
  return u;
}

// ------ in_proj stage 1, LAYER 0: embed-gather + in-block rmsnorm prologue ---
__global__ __launch_bounds__(256)
void k_inproj1_first(const int* __restrict__ ids, const float* __restrict__ emb,
                     const float* __restrict__ lnw, const float* __restrict__ W,
                     float* __restrict__ pin) {
  __shared__ float xs[8][64];
  __shared__ float sred[4][8];
  int tid = threadIdx.x, lane = tid & 63, wid = tid >> 6;
  int jt = blockIdx.x % 9, kt = blockIdx.x / 9;
  int k0 = kt * 64;
  float ssq[8];
  #pragma unroll
  for (int r = 0; r < 8; ++r) {
    const float* row = emb + (size_t)ids[r] * D_;
    f32x4 a = *reinterpret_cast<const f32x4*>(row + tid * 8);
    f32x4 c = *reinterpret_cast<const f32x4*>(row + tid * 8 + 4);
    ssq[r] = a[0]*a[0] + a[1]*a[1] + a[2]*a[2] + a[3]*a[3]
           + c[0]*c[0] + c[1]*c[1] + c[2]*c[2] + c[3]*c[3];
  }
  #pragma unroll
  for (int r = 0; r < 8; ++r) {
    float wsum = wave_sum(ssq[r]);
    if (lane == 0) sred[wid][r] = wsum;
  }
  __syncthreads();
  for (int i = tid; i < 8 * 64; i += 256) {
    int r = i >> 6, kk = i & 63;
    const float* row = emb + (size_t)ids[r] * D_;
    float tot = sred[0][r] + sred[1][r] + sred[2][r] + sred[3][r];
    float scale = rsqrtf(tot / (float)D_ + EPSF);
    xs[r][kk] = row[k0 + kk] * scale * lnw[k0 + kk];
  }
  __syncthreads();
  int j = jt * 1024 + tid * 4;
  if (j >= DOUT) return;
  f32x4 acc[8];
  #pragma unroll
  for (int r = 0; r < 8; ++r) acc[r] = (f32x4)0.f;
  const float* Wp = W + (size_t)k0 * DOUT + j;
  for (int kk = 0; kk < 64; ++kk) {
    f32x4 w4 = __builtin_nontemporal_load(
        reinterpret_cast<const f32x4*>(Wp + (size_t)kk * DOUT));
    #pragma unroll
    for (int r = 0; r < 8; ++r) acc[r] += w4 * xs[r][kk];
  }
  #pragma unroll
  for (int r = 0; r < 8; ++r)
    *reinterpret_cast<f32x4*>(&pin[((size_t)kt * 8 + r) * DOUT + j]) = acc[r];
}

// ------ in_proj stage 1, layers 1-3: 288 blocks, norm via ssq_in -------------
__global__ __launch_bounds__(256)
void k_inproj1(const float* __restrict__ res, const float* __restrict__ ssq_in,
               const float* __restrict__ lnw, const float* __restrict__ W,
               float* __restrict__ pin) {
  __shared__ float xs[8][64];
  int tid = threadIdx.x;
  int jt = blockIdx.x % 9, kt = blockIdx.x / 9;
  int k0 = kt * 64;
  for (int i = tid; i < 8 * 64; i += 256) {
    int r = i >> 6, kk = i & 63;
    float scale = rsqrtf(ssq_in[r] / (float)D_ + EPSF);
    xs[r][kk] = res[r * D_ + k0 + kk] * scale * lnw[k0 + kk];
  }
  __syncthreads();
  int j = jt * 1024 + tid * 4;
  if (j >= DOUT) return;
  f32x4 acc[8];
  #pragma unroll
  for (int r = 0; r < 8; ++r) acc[r] = (f32x4)0.f;
  const float* Wp = W + (size_t)k0 * DOUT + j;
  for (int kk = 0; kk < 64; ++kk) {
    f32x4 w4 = __builtin_nontemporal_load(
        reinterpret_cast<const f32x4*>(Wp + (size_t)kk * DOUT));
    #pragma unroll
    for (int r = 0; r < 8; ++r) acc[r] += w4 * xs[r][kk];
  }
  #pragma unroll
  for (int r = 0; r < 8; ++r)
    *reinterpret_cast<f32x4*>(&pin[((size_t)kt * 8 + r) * DOUT + j]) = acc[r];
}

// ------- in_proj stage 2: reduce partials -> zx, fused conv+dt+softmax;
// ------- block 0 zeroes ssq_in (next-layer accum) and gssq (state accum).
__global__ __launch_bounds__(256)
void k_inproj2_conv(const float* __restrict__ pin, const float* __restrict__ conv_state,
                    const float* __restrict__ conv_w, const float* __restrict__ conv_b,
                    const float* __restrict__ A_log, const float* __restrict__ dt_bias,
                    const float* __restrict__ W_mc,
                    float* __restrict__ zx, float* __restrict__ xbc,
                    float* __restrict__ dts, float* __restrict__ dav,
                    float* __restrict__ wmc, float* __restrict__ ssq_in,
                    float* __restrict__ gssq) {
  if (blockIdx.x == 0) {
    if (threadIdx.x < 8) ssq_in[threadIdx.x] = 0.f;
    else if (threadIdx.x < 16) gssq[threadIdx.x - 8] = 0.f;
  }
  const int TOT4 = B_ * DOUT / 4;   // 17024
  int t = blockIdx.x * 256 + threadIdx.x;
  if (t >= TOT4) return;
  f32x4 s = (f32x4)0.f;
  const f32x4* p4 = reinterpret_cast<const f32x4*>(pin) + t;
  #pragma unroll 8
  for (int kt = 0; kt < KT_IN; ++kt) s += p4[(size_t)kt * TOT4];
  reinterpret_cast<f32x4*>(zx)[t] = s;
  int c4 = t * 4;
  int b = c4 / DOUT;
  int c = c4 - b * DOUT;
  #pragma unroll
  for (int e = 0; e < 4; ++e) {
    int ce = c + e;
    if (ce >= DI && ce < DI + CCH) {
      int cc = ce - DI;
      f32x4 cs4 = *reinterpret_cast<const f32x4*>(conv_state + ((size_t)b * CCH + cc) * K_);
      f32x4 cw4 = *reinterpret_cast<const f32x4*>(conv_w + (size_t)cc * K_);
      float v = cs4[1] * cw4[0] + cs4[2] * cw4[1] + cs4[3] * cw4[2]
              + s[e] * cw4[3] + conv_b[cc];
      xbc[b * CCH + cc] = v / (1.f + expf(-v));   // silu
    } else if (ce >= DI + CCH) {
      int h = ce - DI - CCH;
      float x = s[e] + dt_bias[h];
      float sp = (x > 20.f) ? x : log1pf(expf(x));  // softplus
      dts[b * 64 + h] = sp;
      dav[b * 64 + h] = expf(-expf(A_log[h]) * sp);
    }
  }
  if (t == 0) {
    float mx = -1e30f;
    for (int i = 0; i < M_ + 1; ++i) mx = fmaxf(mx, W_mc[i]);
    float e2[M_ + 1], sum = 0.f;
    for (int i = 0; i < M_ + 1; ++i) { e2[i] = expf(W_mc[i] - mx); sum += e2[i]; }
    for (int i = 0; i < M_ + 1; ++i) wmc[i] = e2[i] / sum;
  }
}

// -------- state update + MC fuse + y, FUSED gated-norm ssq accumulation ------
// (R12 state + writer lanes compute v=y*silu(z), LDS-reduce v^2, one
//  atomicAdd per block into gssq[b]; b is uniform per block.)
__global__ __launch_bounds__(256)
void k_state(const float* __restrict__ xbc, const float* __restrict__ zx,
             const float* __restrict__ dts, const float* __restrict__ dav,
             const float* __restrict__ Dp_, const float* __restrict__ wmc,
             const float* __restrict__ ssm, const float* __restrict__ cached,
             float* __restrict__ y, float* __restrict__ gssq) {
  __shared__ float gred[8];
  int wg = blockIdx.x * 4 + (threadIdx.x >> 6);   // [0, 16384)
  int lane = threadIdx.x & 63;
  int b = wg >> 11;                               // uniform per block
  int h = (wg >> 5) & 63;
  int pp = wg & 31;
  int hf = lane >> 5, il = lane & 31;
  int p = pp * 2 + hf;
  float xv  = xbc[b * CCH + h * 64 + p];
  float dtv = dts[b * 64 + h];
  float da  = dav[b * 64 + h];
  float w8  = wmc[8];
  const f32x4* xb4 = reinterpret_cast<const f32x4*>(xbc);
  f32x4 B4 = xb4[b * (CCH / 4) + DI / 4 + il];
  f32x4 C4 = xb4[b * (CCH / 4) + DI / 4 + N_ / 4 + il];
  const f32x4* sp4 = reinterpret_cast<const f32x4*>(ssm) +
                     ((size_t)((b * H_ + h) * P_ + p)) * (N_ / 4) + il;
  const f32x4* cp4 = reinterpret_cast<const f32x4*>(cached) +
                     ((size_t)(((b * M_) * H_ + h) * P_ + p)) * (N_ / 4) + il;
  f32x4 s4 = __builtin_nontemporal_load(sp4);
  f32x4 f4 = (s4 * da + B4 * (dtv * xv)) * w8;
  #pragma unroll
  for (int m = 0; m < 8; ++m) {
    f32x4 c4 = __builtin_nontemporal_load(cp4 + (size_t)m * (H_ * P_ * N_ / 4));
    f4 += c4 * wmc[m];
  }
  f4 *= C4;
  float acc = f4[0] + f4[1] + f4[2] + f4[3];
  #pragma unroll
  for (int off = 1; off < 32; off <<= 1) acc += __shfl_xor(acc, off, 64);
  if (il == 0) {
    float yv = acc + Dp_[h] * xv;
    int d = h * 64 + p;
    y[b * DI + d] = yv;
    float z = zx[b * DOUT + d];
    float v = yv * (z / (1.f + expf(-z)));
    gred[(threadIdx.x >> 6) * 2 + hf] = v * v;
  }
  __syncthreads();
  if (threadIdx.x == 0) {
    float g = gred[0] + gred[1] + gred[2] + gred[3]
            + gred[4] + gred[5] + gred[6] + gred[7];
    atomicAdd(&gssq[b], g);
  }
}

// ------ out_proj stage 1, gated-norm applied inline during staging -----------
// (1 expf per thread — staging slice is 8x32 = 256 elements = 1/thread.)
__global__ void k_outproj1(const float* __restrict__ y, const float* __restrict__ zx,
                           const float* __restrict__ mnw, const float* __restrict__ gssq,
                           const float* __restrict__ W, float* __restrict__ pout) {
  __shared__ float xs[8][32];
  int tid = threadIdx.x;
  int jt = blockIdx.x & 1, kt = blockIdx.x >> 1;
  int k0 = kt * 32;
  {
    int r = tid >> 5, kk = tid & 31;
    float scale = rsqrtf(gssq[r] / (float)DI + EPSF);
    float z = zx[r * DOUT + k0 + kk];
    float g = z / (1.f + expf(-z));
    xs[r][kk] = y[r * DI + k0 + kk] * g * scale * mnw[k0 + kk];
  }
  __syncthreads();
  int j = jt * 1024 + tid * 4;
  f32x4 acc[8];
  #pragma unroll
  for (int r = 0; r < 8; ++r) acc[r] = (f32x4)0.f;
  const float* Wp = W + (size_t)k0 * D_ + j;
  for (int kk = 0; kk < 32; ++kk) {
    f32x4 w4 = __builtin_nontemporal_load(
        reinterpret_cast<const f32x4*>(Wp + (size_t)kk * D_));
    #pragma unroll
    for (int r = 0; r < 8; ++r) acc[r] += w4 * xs[r][kk];
  }
  #pragma unroll
  for (int r = 0; r < 8; ++r)
    *reinterpret_cast<f32x4*>(&pout[((size_t)kt * 8 + r) * D_ + j]) = acc[r];
}

// ------- out_proj stage 2: reduce partials; L0 (ids): res = emb[ids]+tot,
// ------- else res += tot; accumulates next-norm ssq_in[row].
__global__ __launch_bounds__(256)
void k_outproj2(const float* __restrict__ pout, float* __restrict__ res,
                const int* __restrict__ ids, const float* __restrict__ emb,
                float* __restrict__ ssq_in) {
  __shared__ f32x4 red[256];
  const int TOT4 = B_ * D_ / 4;   // 4096
  int tid = threadIdx.x;
  int pos = blockIdx.x * 64 + (tid & 63);
  int kq = tid >> 6;              // wave index = kt quarter
  const f32x4* p4 = reinterpret_cast<const f32x4*>(pout) + pos;
  f32x4 s = (f32x4)0.f;
  #pragma unroll 8
  for (int k = 0; k < 32; ++k)
    s += p4[(size_t)(kq * 32 + k) * TOT4];
  red[tid] = s;
  __syncthreads();
  if (tid < 64) {
    f32x4 tot = red[tid] + red[tid + 64] + red[tid + 128] + red[tid + 192];
    f32x4* r4 = reinterpret_cast<f32x4*>(res);
    f32x4 nv;
    if (ids) {
      int b = pos >> 9, d4 = pos & 511;
      f32x4 base = reinterpret_cast<const f32x4*>(emb)[(size_t)ids[b] * (D_ / 4) + d4];
      nv = base + tot;
    } else {
      nv = r4[pos] + tot;
    }
    r4[pos] = nv;
    float ps = nv[0]*nv[0] + nv[1]*nv[1] + nv[2]*nv[2] + nv[3]*nv[3];
    ps = wave_sum(ps);
    if (tid == 0) atomicAdd(&ssq_in[pos >> 9], ps);
  }
}

// ---------------- logits: wave-per-row, split-D (SL=4), FUSED final norm -----
#define SL_ 4
#define KS_ (D_ / SL_)            // 512
#define NVB16 (V_ / 16)           // 3143 (exact)
__global__ __launch_bounds__(256)
void k_logits(const float* __restrict__ res, const float* __restrict__ ssq_in,
              const float* __restrict__ nfw, const float* __restrict__ emb,
              float* __restrict__ pl) {
  __shared__ f32x4 xs[8][KS_ / 4];   // 16 KB -> 8 blocks/CU, 32 waves/CU
  int s = blockIdx.x & 3, vb = blockIdx.x >> 2;
  const f32x4* res4 = reinterpret_cast<const f32x4*>(res);
  const f32x4* nfw4 = reinterpret_cast<const f32x4*>(nfw);
  for (int i = threadIdx.x; i < 8 * (KS_ / 4); i += 256) {
    int r = i >> 7, q = i & 127;
    float scale = rsqrtf(ssq_in[r] / (float)D_ + EPSF);
    xs[r][q] = res4[r * (D_ / 4) + s * (KS_ / 4) + q] * scale
             * nfw4[s * (KS_ / 4) + q];
  }
  __syncthreads();
  int wid = threadIdx.x >> 6, lane = threadIdx.x & 63;
  int v0 = vb * 16 + wid * 4;
  const f32x4* e4 = reinterpret_cast<const f32x4*>(emb);
  #pragma unroll
  for (int vv = 0; vv < 4; ++vv) {
    int v = v0 + vv;
    const f32x4* ep = e4 + (size_t)v * (D_ / 4) + s * (KS_ / 4);
    float acc[8] = {0,0,0,0,0,0,0,0};
    #pragma unroll
    for (int st = 0; st < KS_ / 256; ++st) {
      int c = st * 64 + lane;
      f32x4 e = __builtin_nontemporal_load(ep + c);
      #pragma unroll
      for (int r = 0; r < 8; ++r) {
        f32x4 x = xs[r][c];
        acc[r] += e[0]*x[0] + e[1]*x[1] + e[2]*x[2] + e[3]*x[3];
      }
    }
    float u = fold_reduce8(acc, lane);
    if (lane < 8) pl[((size_t)s * 8 + lane) * V_ + v] = u;
  }
}

// ---------------- logits combine: out = sum of 4 slice partials --------------
__global__ __launch_bounds__(256)
void k_logits2(const float* __restrict__ pl, float* __restrict__ out) {
  int v = blockIdx.x * 256 + threadIdx.x;
  if (v >= V_) return;
  int r = blockIdx.y;
  float t = pl[(size_t)r * V_ + v]
          + pl[((size_t)8  + r) * V_ + v]
          + pl[((size_t)16 + r) * V_ + v]
          + pl[((size_t)24 + r) * V_ + v];
  out[(size_t)r * V_ + v] = t;
}

extern "C" void kernel_launch(void* const* d_in, const int* in_sizes, int n_in,
                              void* d_out, int out_size, void* d_ws, size_t ws_size,
                              hipStream_t stream) {
  const int*   ids    = (const int*)  d_in[0];
  const float* emb    = (const float*)d_in[1];
  const float* inW    = (const float*)d_in[2];
  const float* convW  = (const float*)d_in[3];
  const float* convB  = (const float*)d_in[4];
  const float* Alog   = (const float*)d_in[5];
  const float* dtB    = (const float*)d_in[6];
  const float* Dpar   = (const float*)d_in[7];
  const float* mnw    = (const float*)d_in[8];
  const float* outW   = (const float*)d_in[9];
  const float* lnw    = (const float*)d_in[10];
  const float* nfw    = (const float*)d_in[11];
  const float* Wmc    = (const float*)d_in[12];
  const float* convS  = (const float*)d_in[13];
  const float* ssmS   = (const float*)d_in[14];
  const float* cached = (const float*)d_in[15];
  float* out = (float*)d_out;
  float* ws  = (float*)d_ws;

  float* res   = ws;            // 16384 floats
  float* zx    = ws + 16384;    // 68096
  float* xbc   = ws + 84480;    // 34816
  float* dts   = ws + 119296;   // 512
  float* dav   = ws + 119808;   // 512
  float* wmc   = ws + 120320;   // 64
  float* ssqi  = ws + 120384;   // 64 (8 used)
  float* gssq  = ws + 120448;   // 64 (8 used)
  float* y     = ws + 120512;   // 32768
  float* pin   = ws + 153280;   // 32*8*8512 = 2179072
  float* pout  = ws + 2332352;  // 128*8*2048 = 2097152
  float* pl    = ws + 4429504;  // 4*8*50288 = 1609216 -> ends 6038720 (~24.2MB)

  for (int l = 0; l < LN; ++l) {
    if (l == 0)
      k_inproj1_first<<<288, 256, 0, stream>>>(ids, emb, lnw, inW, pin);
    else
      k_inproj1<<<288, 256, 0, stream>>>(res, ssqi, lnw + (size_t)l * D_,
                                         inW + (size_t)l * D_ * DOUT, pin);
    k_inproj2_conv<<<67, 256, 0, stream>>>(pin,
        convS + (size_t)l * B_ * CCH * K_, convW + (size_t)l * CCH * K_,
        convB + (size_t)l * CCH, Alog + l * H_, dtB + l * H_, Wmc + l * (M_ + 1),
        zx, xbc, dts, dav, wmc, ssqi, gssq);
    k_state<<<4096, 256, 0, stream>>>(xbc, zx, dts, dav, Dpar + l * H_, wmc,
        ssmS + (size_t)l * B_ * H_ * P_ * N_,
        cached + (size_t)l * B_ * M_ * H_ * P_ * N_, y, gssq);
    k_outproj1<<<256, 256, 0, stream>>>(y, zx, mnw + (size_t)l * DI, gssq,
                                        outW + (size_t)l * DI * D_, pout);
    k_outproj2<<<64, 256, 0, stream>>>(pout, res,
                                       (l == 0) ? ids : nullptr, emb, ssqi);
  }
  k_logits<<<NVB16 * SL_, 256, 0, stream>>>(res, ssqi, nfw, emb, pl);
  k_logits2<<<dim3((V_ + 255) / 256, 8), 256, 0, stream>>>(pl, out);
}

// Round 15
// 418.585 us; speedup vs baseline: 5.7395x; 1.3253x over previous
//
#include <hip/hip_runtime.h>
#include <hip/hip_bf16.h>
#include <math.h>

#define LN 4
#define B_ 8
#define D_ 2048
#define DI 4096
#define N_ 128
#define H_ 64
#define P_ 64
#define K_ 4
#define M_ 8
#define V_ 50288
#define CCH (DI + 2*N_)           // 4352
#define DOUT (2*DI + 2*N_ + H_)   // 8512
#define EPSF 1e-5f
#define KT_IN 32                  // in_proj k-tiles (k0=64)
#define KT_OUT 128                // out_proj k-tiles (k0=32)
#define SSQS 16                   // ssq_in stride (floats) -> one cache line each

typedef float f32x4 __attribute__((ext_vector_type(4)));

__device__ inline float wave_sum(float v) {
  #pragma unroll
  for (int off = 32; off > 0; off >>= 1) v += __shfl_xor(v, off, 64);
  return v;
}

// Fold-reduce 8 per-lane accumulators: lane l gets full 64-lane sum of a[l&7].
__device__ inline float fold_reduce8(const float a[8], int lane) {
  float t0[4];
  #pragma unroll
  for (int r = 0; r < 4; ++r) {
    float keep = (lane & 1) ? a[2*r+1] : a[2*r];
    float send = (lane & 1) ? a[2*r]   : a[2*r+1];
    t0[r] = keep + __shfl_xor(send, 1, 64);
  }
  float t1[2];
  #pragma unroll
  for (int r = 0; r < 2; ++r) {
    float keep = (lane & 2) ? t0[2*r+1] : t0[2*r];
    float send = (lane & 2) ? t0[2*r]   : t0[2*r+1];
    t1[r] = keep + __shfl_xor(send, 2, 64);
  }
  float keep = (lane & 4) ? t1[1] : t1[0];
  float send = (lane & 4) ? t1[0] : t1[1];
  float u = keep + __shfl_xor(send, 4, 64);
  u += __shfl_xor(u, 8, 64);
  u += __shfl_xor(u, 16, 64);
  u += __shfl_xor(u, 32, 64);
  return u;
}

// ------ in_proj stage 1, LAYER 0: embed-gather + in-block rmsnorm prologue ---
__global__ __launch_bounds__(256)
void k_inproj1_first(const int* __restrict__ ids, const float* __restrict__ emb,
                     const float* __restrict__ lnw, const float* __restrict__ W,
                     float* __restrict__ pin) {
  __shared__ float xs[8][64];
  __shared__ float sred[4][8];
  int tid = threadIdx.x, lane = tid & 63, wid = tid >> 6;
  int jt = blockIdx.x % 9, kt = blockIdx.x / 9;
  int k0 = kt * 64;
  float ssq[8];
  #pragma unroll
  for (int r = 0; r < 8; ++r) {
    const float* row = emb + (size_t)ids[r] * D_;
    f32x4 a = *reinterpret_cast<const f32x4*>(row + tid * 8);
    f32x4 c = *reinterpret_cast<const f32x4*>(row + tid * 8 + 4);
    ssq[r] = a[0]*a[0] + a[1]*a[1] + a[2]*a[2] + a[3]*a[3]
           + c[0]*c[0] + c[1]*c[1] + c[2]*c[2] + c[3]*c[3];
  }
  #pragma unroll
  for (int r = 0; r < 8; ++r) {
    float wsum = wave_sum(ssq[r]);
    if (lane == 0) sred[wid][r] = wsum;
  }
  __syncthreads();
  for (int i = tid; i < 8 * 64; i += 256) {
    int r = i >> 6, kk = i & 63;
    const float* row = emb + (size_t)ids[r] * D_;
    float tot = sred[0][r] + sred[1][r] + sred[2][r] + sred[3][r];
    float scale = rsqrtf(tot / (float)D_ + EPSF);
    xs[r][kk] = row[k0 + kk] * scale * lnw[k0 + kk];
  }
  __syncthreads();
  int j = jt * 1024 + tid * 4;
  if (j >= DOUT) return;
  f32x4 acc[8];
  #pragma unroll
  for (int r = 0; r < 8; ++r) acc[r] = (f32x4)0.f;
  const float* Wp = W + (size_t)k0 * DOUT + j;
  for (int kk = 0; kk < 64; ++kk) {
    f32x4 w4 = __builtin_nontemporal_load(
        reinterpret_cast<const f32x4*>(Wp + (size_t)kk * DOUT));
    #pragma unroll
    for (int r = 0; r < 8; ++r) acc[r] += w4 * xs[r][kk];
  }
  #pragma unroll
  for (int r = 0; r < 8; ++r)
    *reinterpret_cast<f32x4*>(&pin[((size_t)kt * 8 + r) * DOUT + j]) = acc[r];
}

// ------ in_proj stage 1, layers 1-3: 288 blocks, norm via ssq_in (stride) ----
__global__ __launch_bounds__(256)
void k_inproj1(const float* __restrict__ res, const float* __restrict__ ssq_in,
               const float* __restrict__ lnw, const float* __restrict__ W,
               float* __restrict__ pin) {
  __shared__ float xs[8][64];
  int tid = threadIdx.x;
  int jt = blockIdx.x % 9, kt = blockIdx.x / 9;
  int k0 = kt * 64;
  for (int i = tid; i < 8 * 64; i += 256) {
    int r = i >> 6, kk = i & 63;
    float scale = rsqrtf(ssq_in[r * SSQS] / (float)D_ + EPSF);
    xs[r][kk] = res[r * D_ + k0 + kk] * scale * lnw[k0 + kk];
  }
  __syncthreads();
  int j = jt * 1024 + tid * 4;
  if (j >= DOUT) return;
  f32x4 acc[8];
  #pragma unroll
  for (int r = 0; r < 8; ++r) acc[r] = (f32x4)0.f;
  const float* Wp = W + (size_t)k0 * DOUT + j;
  for (int kk = 0; kk < 64; ++kk) {
    f32x4 w4 = __builtin_nontemporal_load(
        reinterpret_cast<const f32x4*>(Wp + (size_t)kk * DOUT));
    #pragma unroll
    for (int r = 0; r < 8; ++r) acc[r] += w4 * xs[r][kk];
  }
  #pragma unroll
  for (int r = 0; r < 8; ++r)
    *reinterpret_cast<f32x4*>(&pin[((size_t)kt * 8 + r) * DOUT + j]) = acc[r];
}

// ------- in_proj stage 2: 266 blocks, 4 threads/element (8 kt-partials each),
// ------- LDS combine, fused conv+dt+softmax epilogue on threads 0..63.
__global__ __launch_bounds__(256)
void k_inproj2_conv(const float* __restrict__ pin, const float* __restrict__ conv_state,
                    const float* __restrict__ conv_w, const float* __restrict__ conv_b,
                    const float* __restrict__ A_log, const float* __restrict__ dt_bias,
                    const float* __restrict__ W_mc,
                    float* __restrict__ zx, float* __restrict__ xbc,
                    float* __restrict__ dts, float* __restrict__ dav,
                    float* __restrict__ wmc) {
  __shared__ f32x4 red[4][64];
  const int TOT4 = B_ * DOUT / 4;   // 17024 = 266 * 64
  int tid = threadIdx.x;
  int el = tid & 63, kq = tid >> 6;
  int e = blockIdx.x * 64 + el;
  f32x4 s = (f32x4)0.f;
  const f32x4* p4 = reinterpret_cast<const f32x4*>(pin) + e;
  #pragma unroll
  for (int kk = 0; kk < 8; ++kk)
    s += p4[(size_t)(kq * 8 + kk) * TOT4];
  red[kq][el] = s;
  __syncthreads();
  if (tid >= 64) return;
  s = red[0][tid] + red[1][tid] + red[2][tid] + red[3][tid];
  reinterpret_cast<f32x4*>(zx)[e] = s;
  int c4 = e * 4;
  int b = c4 / DOUT;
  int c = c4 - b * DOUT;
  #pragma unroll
  for (int q = 0; q < 4; ++q) {
    int ce = c + q;
    if (ce >= DI && ce < DI + CCH) {
      int cc = ce - DI;
      f32x4 cs4 = *reinterpret_cast<const f32x4*>(conv_state + ((size_t)b * CCH + cc) * K_);
      f32x4 cw4 = *reinterpret_cast<const f32x4*>(conv_w + (size_t)cc * K_);
      float v = cs4[1] * cw4[0] + cs4[2] * cw4[1] + cs4[3] * cw4[2]
              + s[q] * cw4[3] + conv_b[cc];
      xbc[b * CCH + cc] = v / (1.f + expf(-v));   // silu
    } else if (ce >= DI + CCH) {
      int h = ce - DI - CCH;
      float x = s[q] + dt_bias[h];
      float sp = (x > 20.f) ? x : log1pf(expf(x));  // softplus
      dts[b * 64 + h] = sp;
      dav[b * 64 + h] = expf(-expf(A_log[h]) * sp);
    }
  }
  if (blockIdx.x == 0 && tid == 0) {
    float mx = -1e30f;
    for (int i = 0; i < M_ + 1; ++i) mx = fmaxf(mx, W_mc[i]);
    float e2[M_ + 1], sum = 0.f;
    for (int i = 0; i < M_ + 1; ++i) { e2[i] = expf(W_mc[i] - mx); sum += e2[i]; }
    for (int i = 0; i < M_ + 1; ++i) wmc[i] = e2[i] / sum;
  }
}

// ---------------- state update + MC fuse + y (R12-exact) ---------------------
__global__ __launch_bounds__(256)
void k_state(const float* __restrict__ xbc, const float* __restrict__ dts,
             const float* __restrict__ dav, const float* __restrict__ Dp_,
             const float* __restrict__ wmc, const float* __restrict__ ssm,
             const float* __restrict__ cached, float* __restrict__ y) {
  int wg = blockIdx.x * 4 + (threadIdx.x >> 6);   // [0, 16384)
  int lane = threadIdx.x & 63;
  int b = wg >> 11;
  int h = (wg >> 5) & 63;
  int pp = wg & 31;
  int hf = lane >> 5, il = lane & 31;
  int p = pp * 2 + hf;
  float xv  = xbc[b * CCH + h * 64 + p];
  float dtv = dts[b * 64 + h];
  float da  = dav[b * 64 + h];
  float w8  = wmc[8];
  const f32x4* xb4 = reinterpret_cast<const f32x4*>(xbc);
  f32x4 B4 = xb4[b * (CCH / 4) + DI / 4 + il];
  f32x4 C4 = xb4[b * (CCH / 4) + DI / 4 + N_ / 4 + il];
  const f32x4* sp4 = reinterpret_cast<const f32x4*>(ssm) +
                     ((size_t)((b * H_ + h) * P_ + p)) * (N_ / 4) + il;
  const f32x4* cp4 = reinterpret_cast<const f32x4*>(cached) +
                     ((size_t)(((b * M_) * H_ + h) * P_ + p)) * (N_ / 4) + il;
  f32x4 s4 = __builtin_nontemporal_load(sp4);
  f32x4 f4 = (s4 * da + B4 * (dtv * xv)) * w8;
  #pragma unroll
  for (int m = 0; m < 8; ++m) {
    f32x4 c4 = __builtin_nontemporal_load(cp4 + (size_t)m * (H_ * P_ * N_ / 4));
    f4 += c4 * wmc[m];
  }
  f4 *= C4;
  float acc = f4[0] + f4[1] + f4[2] + f4[3];
  #pragma unroll
  for (int off = 1; off < 32; off <<= 1) acc += __shfl_xor(acc, off, 64);
  if (il == 0) y[b * DI + h * 64 + p] = acc + Dp_[h] * xv;
}

// -------- gated RMS norm: 1024 threads/row (4x parallelism), zero ssq_in -----
__global__ __launch_bounds__(1024)
void k_gatednorm(const float* __restrict__ y, const float* __restrict__ zx,
                 const float* __restrict__ mnw, float* __restrict__ yg,
                 float* __restrict__ ssq_in) {
  __shared__ float lds[16];
  int b = blockIdx.x, tid = threadIdx.x;
  if (tid < 8) ssq_in[tid * SSQS] = 0.f;
  float tv[4];
  float ss = 0.f;
  #pragma unroll
  for (int t = 0; t < 4; ++t) {
    int i = tid + t * 1024;
    float z = zx[b * DOUT + i];
    float v = y[b * DI + i] * (z / (1.f + expf(-z)));
    tv[t] = v; ss += v * v;
  }
  float wsum = wave_sum(ss);
  int lane = tid & 63, wid = tid >> 6;
  if (lane == 0) lds[wid] = wsum;
  __syncthreads();
  float tot = 0.f;
  #pragma unroll
  for (int i = 0; i < 16; ++i) tot += lds[i];
  float scale = rsqrtf(tot / (float)DI + EPSF);
  #pragma unroll
  for (int t = 0; t < 4; ++t) {
    int i = tid + t * 1024;
    yg[b * DI + i] = tv[t] * scale * mnw[i];
  }
}

// ---------------- out_proj stage 1 (R12-exact): partials, no atomics ---------
__global__ void k_outproj1(const float* __restrict__ yg, const float* __restrict__ W,
                           float* __restrict__ pout) {
  __shared__ float xs[8][32];
  int jt = blockIdx.x & 1, kt = blockIdx.x >> 1;
  int k0 = kt * 32;
  for (int i = threadIdx.x; i < 8 * 32; i += 256) {
    int r = i >> 5, kk = i & 31;
    xs[r][kk] = yg[r * DI + k0 + kk];
  }
  __syncthreads();
  int j = jt * 1024 + threadIdx.x * 4;
  f32x4 acc[8];
  #pragma unroll
  for (int r = 0; r < 8; ++r) acc[r] = (f32x4)0.f;
  const float* Wp = W + (size_t)k0 * D_ + j;
  for (int kk = 0; kk < 32; ++kk) {
    f32x4 w4 = __builtin_nontemporal_load(
        reinterpret_cast<const f32x4*>(Wp + (size_t)kk * D_));
    #pragma unroll
    for (int r = 0; r < 8; ++r) acc[r] += w4 * xs[r][kk];
  }
  #pragma unroll
  for (int r = 0; r < 8; ++r)
    *reinterpret_cast<f32x4*>(&pout[((size_t)kt * 8 + r) * D_ + j]) = acc[r];
}

// ------- out_proj stage 2: 256 blocks (full chip), 16 pos x 16 kq threads,
// ------- LDS combine; res update + next-norm ssq_in accumulation.
__global__ __launch_bounds__(256)
void k_outproj2(const float* __restrict__ pout, float* __restrict__ res,
                const int* __restrict__ ids, const float* __restrict__ emb,
                float* __restrict__ ssq_in) {
  __shared__ f32x4 red[16][16];
  const int TOT4 = B_ * D_ / 4;   // 4096
  int tid = threadIdx.x;
  int pl = tid & 15, kq = tid >> 4;   // 16 pos x 16 kq (8 kt each)
  int pos = blockIdx.x * 16 + pl;
  const f32x4* p4 = reinterpret_cast<const f32x4*>(pout) + pos;
  f32x4 s = (f32x4)0.f;
  #pragma unroll
  for (int kk = 0; kk < 8; ++kk)
    s += p4[(size_t)(kq * 8 + kk) * TOT4];
  red[pl][kq] = s;
  __syncthreads();
  if (tid < 16) {
    f32x4 tot = (f32x4)0.f;
    #pragma unroll
    for (int q = 0; q < 16; ++q) tot += red[tid][q];
    int mypos = blockIdx.x * 16 + tid;
    f32x4* r4 = reinterpret_cast<f32x4*>(res);
    f32x4 nv;
    if (ids) {
      int b = mypos >> 9, d4 = mypos & 511;
      f32x4 base = reinterpret_cast<const f32x4*>(emb)[(size_t)ids[b] * (D_ / 4) + d4];
      nv = base + tot;
    } else {
      nv = r4[mypos] + tot;
    }
    r4[mypos] = nv;
    float ps = nv[0]*nv[0] + nv[1]*nv[1] + nv[2]*nv[2] + nv[3]*nv[3];
    #pragma unroll
    for (int off = 1; off < 16; off <<= 1) ps += __shfl_xor(ps, off, 64);
    if (tid == 0) atomicAdd(&ssq_in[(mypos >> 9) * SSQS], ps);
  }
}

// ---------------- logits: wave-per-row, split-D (SL=4), FUSED final norm -----
#define SL_ 4
#define KS_ (D_ / SL_)            // 512
#define NVB16 (V_ / 16)           // 3143 (exact)
__global__ __launch_bounds__(256)
void k_logits(const float* __restrict__ res, const float* __restrict__ ssq_in,
              const float* __restrict__ nfw, const float* __restrict__ emb,
              float* __restrict__ pl) {
  __shared__ f32x4 xs[8][KS_ / 4];   // 16 KB -> 8 blocks/CU, 32 waves/CU
  int s = blockIdx.x & 3, vb = blockIdx.x >> 2;
  const f32x4* res4 = reinterpret_cast<const f32x4*>(res);
  const f32x4* nfw4 = reinterpret_cast<const f32x4*>(nfw);
  for (int i = threadIdx.x; i < 8 * (KS_ / 4); i += 256) {
    int r = i >> 7, q = i & 127;
    float scale = rsqrtf(ssq_in[r * SSQS] / (float)D_ + EPSF);
    xs[r][q] = res4[r * (D_ / 4) + s * (KS_ / 4) + q] * scale
             * nfw4[s * (KS_ / 4) + q];
  }
  __syncthreads();
  int wid = threadIdx.x >> 6, lane = threadIdx.x & 63;
  int v0 = vb * 16 + wid * 4;
  const f32x4* e4 = reinterpret_cast<const f32x4*>(emb);
  #pragma unroll
  for (int vv = 0; vv < 4; ++vv) {
    int v = v0 + vv;
    const f32x4* ep = e4 + (size_t)v * (D_ / 4) + s * (KS_ / 4);
    float acc[8] = {0,0,0,0,0,0,0,0};
    #pragma unroll
    for (int st = 0; st < KS_ / 256; ++st) {
      int c = st * 64 + lane;
      f32x4 e = __builtin_nontemporal_load(ep + c);
      #pragma unroll
      for (int r = 0; r < 8; ++r) {
        f32x4 x = xs[r][c];
        acc[r] += e[0]*x[0] + e[1]*x[1] + e[2]*x[2] + e[3]*x[3];
      }
    }
    float u = fold_reduce8(acc, lane);
    if (lane < 8) pl[((size_t)s * 8 + lane) * V_ + v] = u;
  }
}

// ---------------- logits combine: out = sum of 4 slice partials --------------
__global__ __launch_bounds__(256)
void k_logits2(const float* __restrict__ pl, float* __restrict__ out) {
  int v = blockIdx.x * 256 + threadIdx.x;
  if (v >= V_) return;
  int r = blockIdx.y;
  float t = pl[(size_t)r * V_ + v]
          + pl[((size_t)8  + r) * V_ + v]
          + pl[((size_t)16 + r) * V_ + v]
          + pl[((size_t)24 + r) * V_ + v];
  out[(size_t)r * V_ + v] = t;
}

extern "C" void kernel_launch(void* const* d_in, const int* in_sizes, int n_in,
                              void* d_out, int out_size, void* d_ws, size_t ws_size,
                              hipStream_t stream) {
  const int*   ids    = (const int*)  d_in[0];
  const float* emb    = (const float*)d_in[1];
  const float* inW    = (const float*)d_in[2];
  const float* convW  = (const float*)d_in[3];
  const float* convB  = (const float*)d_in[4];
  const float* Alog   = (const float*)d_in[5];
  const float* dtB    = (const float*)d_in[6];
  const float* Dpar   = (const float*)d_in[7];
  const float* mnw    = (const float*)d_in[8];
  const float* outW   = (const float*)d_in[9];
  const float* lnw    = (const float*)d_in[10];
  const float* nfw    = (const float*)d_in[11];
  const float* Wmc    = (const float*)d_in[12];
  const float* convS  = (const float*)d_in[13];
  const float* ssmS   = (const float*)d_in[14];
  const float* cached = (const float*)d_in[15];
  float* out = (float*)d_out;
  float* ws  = (float*)d_ws;

  float* res   = ws;            // 16384 floats
  float* zx    = ws + 16384;    // 68096
  float* xbc   = ws + 84480;    // 34816
  float* dts   = ws + 119296;   // 512
  float* dav   = ws + 119808;   // 512
  float* wmc   = ws + 120320;   // 64
  float* ssqi  = ws + 120384;   // 128 (8 used, stride 16)
  float* y     = ws + 120512;   // 32768
  float* yg    = ws + 153280;   // 32768
  float* pin   = ws + 186048;   // 32*8*8512 = 2179072
  float* pout  = ws + 2365120;  // 128*8*2048 = 2097152
  float* pl    = ws + 4462272;  // 4*8*50288 = 1609216 -> ends 6071488 (~24.3MB)

  for (int l = 0; l < LN; ++l) {
    if (l == 0)
      k_inproj1_first<<<288, 256, 0, stream>>>(ids, emb, lnw, inW, pin);
    else
      k_inproj1<<<288, 256, 0, stream>>>(res, ssqi, lnw + (size_t)l * D_,
                                         inW + (size_t)l * D_ * DOUT, pin);
    k_inproj2_conv<<<266, 256, 0, stream>>>(pin,
        convS + (size_t)l * B_ * CCH * K_, convW + (size_t)l * CCH * K_,
        convB + (size_t)l * CCH, Alog + l * H_, dtB + l * H_, Wmc + l * (M_ + 1),
        zx, xbc, dts, dav, wmc);
    k_state<<<4096, 256, 0, stream>>>(xbc, dts, dav, Dpar + l * H_, wmc,
        ssmS + (size_t)l * B_ * H_ * P_ * N_,
        cached + (size_t)l * B_ * M_ * H_ * P_ * N_, y);
    k_gatednorm<<<8, 1024, 0, stream>>>(y, zx, mnw + (size_t)l * DI, yg, ssqi);
    k_outproj1<<<256, 256, 0, stream>>>(yg, outW + (size_t)l * DI * D_, pout);
    k_outproj2<<<256, 256, 0, stream>>>(pout, res,
                                        (l == 0) ? ids : nullptr, emb, ssqi);
  }
  k_logits<<<NVB16 * SL_, 256, 0, stream>>>(res, ssqi, nfw, emb, pl);
  k_logits2<<<dim3((V_ + 255) / 256, 8), 256, 0, stream>>>(pl, out);
}

// Round 16
// 410.558 us; speedup vs baseline: 5.8517x; 1.0196x over previous
//
#include <hip/hip_runtime.h>
#include <hip/hip_bf16.h>
#include <math.h>

#define LN 4
#define B_ 8
#define D_ 2048
#define DI 4096
#define N_ 128
#define H_ 64
#define P_ 64
#define K_ 4
#define M_ 8
#define V_ 50288
#define CCH (DI + 2*N_)           // 4352
#define DOUT (2*DI + 2*N_ + H_)   // 8512
#define EPSF 1e-5f
#define KT_IN 32                  // in_proj k-tiles (k0=64)
#define KT_OUT 128                // out_proj k-tiles (k0=32)
#define SSQS 16                   // ssq_in stride (floats) -> one cache line each

typedef float f32x4 __attribute__((ext_vector_type(4)));

__device__ inline float wave_sum(float v) {
  #pragma unroll
  for (int off = 32; off > 0; off >>= 1) v += __shfl_xor(v, off, 64);
  return v;
}

// Fold-reduce 8 per-lane accumulators: lane l gets full 64-lane sum of a[l&7].
__device__ inline float fold_reduce8(const float a[8], int lane) {
  float t0[4];
  #pragma unroll
  for (int r = 0; r < 4; ++r) {
    float keep = (lane & 1) ? a[2*r+1] : a[2*r];
    float send = (lane & 1) ? a[2*r]   : a[2*r+1];
    t0[r] = keep + __shfl_xor(send, 1, 64);
  }
  float t1[2];
  #pragma unroll
  for (int r = 0; r < 2; ++r) {
    float keep = (lane & 2) ? t0[2*r+1] : t0[2*r];
    float send = (lane & 2) ? t0[2*r]   : t0[2*r+1];
    t1[r] = keep + __shfl_xor(send, 2, 64);
  }
  float keep = (lane & 4) ? t1[1] : t1[0];
  float send = (lane & 4) ? t1[0] : t1[1];
  float u = keep + __shfl_xor(send, 4, 64);
  u += __shfl_xor(u, 8, 64);
  u += __shfl_xor(u, 16, 64);
  u += __shfl_xor(u, 32, 64);
  return u;
}

// ------ in_proj stage 1, LAYER 0: embed-gather + in-block rmsnorm prologue ---
__global__ __launch_bounds__(256)
void k_inproj1_first(const int* __restrict__ ids, const float* __restrict__ emb,
                     const float* __restrict__ lnw, const float* __restrict__ W,
                     float* __restrict__ pin) {
  __shared__ float xs[8][64];
  __shared__ float sred[4][8];
  int tid = threadIdx.x, lane = tid & 63, wid = tid >> 6;
  int jt = blockIdx.x % 9, kt = blockIdx.x / 9;
  int k0 = kt * 64;
  float ssq[8];
  #pragma unroll
  for (int r = 0; r < 8; ++r) {
    const float* row = emb + (size_t)ids[r] * D_;
    f32x4 a = *reinterpret_cast<const f32x4*>(row + tid * 8);
    f32x4 c = *reinterpret_cast<const f32x4*>(row + tid * 8 + 4);
    ssq[r] = a[0]*a[0] + a[1]*a[1] + a[2]*a[2] + a[3]*a[3]
           + c[0]*c[0] + c[1]*c[1] + c[2]*c[2] + c[3]*c[3];
  }
  #pragma unroll
  for (int r = 0; r < 8; ++r) {
    float wsum = wave_sum(ssq[r]);
    if (lane == 0) sred[wid][r] = wsum;
  }
  __syncthreads();
  for (int i = tid; i < 8 * 64; i += 256) {
    int r = i >> 6, kk = i & 63;
    const float* row = emb + (size_t)ids[r] * D_;
    float tot = sred[0][r] + sred[1][r] + sred[2][r] + sred[3][r];
    float scale = rsqrtf(tot / (float)D_ + EPSF);
    xs[r][kk] = row[k0 + kk] * scale * lnw[k0 + kk];
  }
  __syncthreads();
  int j = jt * 1024 + tid * 4;
  if (j >= DOUT) return;
  f32x4 acc[8];
  #pragma unroll
  for (int r = 0; r < 8; ++r) acc[r] = (f32x4)0.f;
  const float* Wp = W + (size_t)k0 * DOUT + j;
  for (int kk = 0; kk < 64; ++kk) {
    f32x4 w4 = __builtin_nontemporal_load(
        reinterpret_cast<const f32x4*>(Wp + (size_t)kk * DOUT));
    #pragma unroll
    for (int r = 0; r < 8; ++r) acc[r] += w4 * xs[r][kk];
  }
  #pragma unroll
  for (int r = 0; r < 8; ++r)
    *reinterpret_cast<f32x4*>(&pin[((size_t)kt * 8 + r) * DOUT + j]) = acc[r];
}

// ------ in_proj stage 1, layers 1-3: 288 blocks, norm via ssq_in (stride) ----
__global__ __launch_bounds__(256)
void k_inproj1(const float* __restrict__ res, const float* __restrict__ ssq_in,
               const float* __restrict__ lnw, const float* __restrict__ W,
               float* __restrict__ pin) {
  __shared__ float xs[8][64];
  int tid = threadIdx.x;
  int jt = blockIdx.x % 9, kt = blockIdx.x / 9;
  int k0 = kt * 64;
  for (int i = tid; i < 8 * 64; i += 256) {
    int r = i >> 6, kk = i & 63;
    float scale = rsqrtf(ssq_in[r * SSQS] / (float)D_ + EPSF);
    xs[r][kk] = res[r * D_ + k0 + kk] * scale * lnw[k0 + kk];
  }
  __syncthreads();
  int j = jt * 1024 + tid * 4;
  if (j >= DOUT) return;
  f32x4 acc[8];
  #pragma unroll
  for (int r = 0; r < 8; ++r) acc[r] = (f32x4)0.f;
  const float* Wp = W + (size_t)k0 * DOUT + j;
  for (int kk = 0; kk < 64; ++kk) {
    f32x4 w4 = __builtin_nontemporal_load(
        reinterpret_cast<const f32x4*>(Wp + (size_t)kk * DOUT));
    #pragma unroll
    for (int r = 0; r < 8; ++r) acc[r] += w4 * xs[r][kk];
  }
  #pragma unroll
  for (int r = 0; r < 8; ++r)
    *reinterpret_cast<f32x4*>(&pin[((size_t)kt * 8 + r) * DOUT + j]) = acc[r];
}

// ------- in_proj stage 2: 266 blocks, 4 threads/element (8 kt-partials each),
// ------- LDS combine, fused conv+dt+softmax epilogue; block 0 zeroes ssq_in.
__global__ __launch_bounds__(256)
void k_inproj2_conv(const float* __restrict__ pin, const float* __restrict__ conv_state,
                    const float* __restrict__ conv_w, const float* __restrict__ conv_b,
                    const float* __restrict__ A_log, const float* __restrict__ dt_bias,
                    const float* __restrict__ W_mc,
                    float* __restrict__ zx, float* __restrict__ xbc,
                    float* __restrict__ dts, float* __restrict__ dav,
                    float* __restrict__ wmc, float* __restrict__ ssq_in) {
  __shared__ f32x4 red[4][64];
  const int TOT4 = B_ * DOUT / 4;   // 17024 = 266 * 64
  int tid = threadIdx.x;
  if (blockIdx.x == 1 && tid < 8) ssq_in[tid * SSQS] = 0.f;
  int el = tid & 63, kq = tid >> 6;
  int e = blockIdx.x * 64 + el;
  f32x4 s = (f32x4)0.f;
  const f32x4* p4 = reinterpret_cast<const f32x4*>(pin) + e;
  #pragma unroll
  for (int kk = 0; kk < 8; ++kk)
    s += p4[(size_t)(kq * 8 + kk) * TOT4];
  red[kq][el] = s;
  __syncthreads();
  if (tid >= 64) return;
  s = red[0][tid] + red[1][tid] + red[2][tid] + red[3][tid];
  reinterpret_cast<f32x4*>(zx)[e] = s;
  int c4 = e * 4;
  int b = c4 / DOUT;
  int c = c4 - b * DOUT;
  #pragma unroll
  for (int q = 0; q < 4; ++q) {
    int ce = c + q;
    if (ce >= DI && ce < DI + CCH) {
      int cc = ce - DI;
      f32x4 cs4 = *reinterpret_cast<const f32x4*>(conv_state + ((size_t)b * CCH + cc) * K_);
      f32x4 cw4 = *reinterpret_cast<const f32x4*>(conv_w + (size_t)cc * K_);
      float v = cs4[1] * cw4[0] + cs4[2] * cw4[1] + cs4[3] * cw4[2]
              + s[q] * cw4[3] + conv_b[cc];
      xbc[b * CCH + cc] = v / (1.f + expf(-v));   // silu
    } else if (ce >= DI + CCH) {
      int h = ce - DI - CCH;
      float x = s[q] + dt_bias[h];
      float sp = (x > 20.f) ? x : log1pf(expf(x));  // softplus
      dts[b * 64 + h] = sp;
      dav[b * 64 + h] = expf(-expf(A_log[h]) * sp);
    }
  }
  if (blockIdx.x == 0 && tid == 0) {
    float mx = -1e30f;
    for (int i = 0; i < M_ + 1; ++i) mx = fmaxf(mx, W_mc[i]);
    float e2[M_ + 1], sum = 0.f;
    for (int i = 0; i < M_ + 1; ++i) { e2[i] = expf(W_mc[i] - mx); sum += e2[i]; }
    for (int i = 0; i < M_ + 1; ++i) wmc[i] = e2[i] / sum;
  }
}

// -------- state update + MC fuse + y; block-local gnorm partial (plain store,
// -------- NO atomics — gpart[bid], 4096 distinct addresses) ------------------
__global__ __launch_bounds__(256)
void k_state(const float* __restrict__ xbc, const float* __restrict__ zx,
             const float* __restrict__ dts, const float* __restrict__ dav,
             const float* __restrict__ Dp_, const float* __restrict__ wmc,
             const float* __restrict__ ssm, const float* __restrict__ cached,
             float* __restrict__ y, float* __restrict__ gpart) {
  __shared__ float gred[8];
  int wg = blockIdx.x * 4 + (threadIdx.x >> 6);   // [0, 16384)
  int lane = threadIdx.x & 63;
  int b = wg >> 11;                               // uniform per block
  int h = (wg >> 5) & 63;
  int pp = wg & 31;
  int hf = lane >> 5, il = lane & 31;
  int p = pp * 2 + hf;
  float xv  = xbc[b * CCH + h * 64 + p];
  float dtv = dts[b * 64 + h];
  float da  = dav[b * 64 + h];
  float w8  = wmc[8];
  const f32x4* xb4 = reinterpret_cast<const f32x4*>(xbc);
  f32x4 B4 = xb4[b * (CCH / 4) + DI / 4 + il];
  f32x4 C4 = xb4[b * (CCH / 4) + DI / 4 + N_ / 4 + il];
  const f32x4* sp4 = reinterpret_cast<const f32x4*>(ssm) +
                     ((size_t)((b * H_ + h) * P_ + p)) * (N_ / 4) + il;
  const f32x4* cp4 = reinterpret_cast<const f32x4*>(cached) +
                     ((size_t)(((b * M_) * H_ + h) * P_ + p)) * (N_ / 4) + il;
  f32x4 s4 = __builtin_nontemporal_load(sp4);
  f32x4 f4 = (s4 * da + B4 * (dtv * xv)) * w8;
  #pragma unroll
  for (int m = 0; m < 8; ++m) {
    f32x4 c4 = __builtin_nontemporal_load(cp4 + (size_t)m * (H_ * P_ * N_ / 4));
    f4 += c4 * wmc[m];
  }
  f4 *= C4;
  float acc = f4[0] + f4[1] + f4[2] + f4[3];
  #pragma unroll
  for (int off = 1; off < 32; off <<= 1) acc += __shfl_xor(acc, off, 64);
  if (il == 0) {
    float yv = acc + Dp_[h] * xv;
    int d = h * 64 + p;
    y[b * DI + d] = yv;
    float z = zx[b * DOUT + d];
    float v = yv * (z / (1.f + expf(-z)));
    gred[(threadIdx.x >> 6) * 2 + hf] = v * v;
  }
  __syncthreads();
  if (threadIdx.x == 0) {
    gpart[blockIdx.x] = gred[0] + gred[1] + gred[2] + gred[3]
                      + gred[4] + gred[5] + gred[6] + gred[7];
  }
}

// ------ out_proj stage 1 with gated-norm: reduces gpart (adds-only, L2-hot),
// ------ stages y*silu(z)*rsqrt(ssq/DI+eps)*mnw (1 expf/thread) ---------------
__global__ __launch_bounds__(256)
void k_outproj1(const float* __restrict__ y, const float* __restrict__ zx,
                const float* __restrict__ mnw, const float* __restrict__ gpart,
                const float* __restrict__ W, float* __restrict__ pout) {
  __shared__ float xs[8][32];
  __shared__ float sred[8];
  int tid = threadIdx.x;
  {
    // reduce gpart[r*512 .. +512) for row r = tid>>5 (32 threads per row)
    int r = tid >> 5, t32 = tid & 31;
    const f32x4* g4 = reinterpret_cast<const f32x4*>(gpart) + r * 128 + t32 * 4;
    f32x4 a = g4[0] + g4[1] + g4[2] + g4[3];
    float s = a[0] + a[1] + a[2] + a[3];
    #pragma unroll
    for (int off = 1; off < 32; off <<= 1) s += __shfl_xor(s, off, 64);
    if (t32 == 0) sred[r] = s;
  }
  __syncthreads();
  int jt = blockIdx.x & 1, kt = blockIdx.x >> 1;
  int k0 = kt * 32;
  {
    int r = tid >> 5, kk = tid & 31;
    float scale = rsqrtf(sred[r] / (float)DI + EPSF);
    float z = zx[r * DOUT + k0 + kk];
    float g = z / (1.f + expf(-z));
    xs[r][kk] = y[r * DI + k0 + kk] * g * scale * mnw[k0 + kk];
  }
  __syncthreads();
  int j = jt * 1024 + tid * 4;
  f32x4 acc[8];
  #pragma unroll
  for (int r = 0; r < 8; ++r) acc[r] = (f32x4)0.f;
  const float* Wp = W + (size_t)k0 * D_ + j;
  for (int kk = 0; kk < 32; ++kk) {
    f32x4 w4 = __builtin_nontemporal_load(
        reinterpret_cast<const f32x4*>(Wp + (size_t)kk * D_));
    #pragma unroll
    for (int r = 0; r < 8; ++r) acc[r] += w4 * xs[r][kk];
  }
  #pragma unroll
  for (int r = 0; r < 8; ++r)
    *reinterpret_cast<f32x4*>(&pout[((size_t)kt * 8 + r) * D_ + j]) = acc[r];
}

// ------- out_proj stage 2: 256 blocks (full chip), 16 pos x 16 kq threads,
// ------- LDS combine; res update + next-norm ssq_in accumulation.
__global__ __launch_bounds__(256)
void k_outproj2(const float* __restrict__ pout, float* __restrict__ res,
                const int* __restrict__ ids, const float* __restrict__ emb,
                float* __restrict__ ssq_in) {
  __shared__ f32x4 red[16][16];
  const int TOT4 = B_ * D_ / 4;   // 4096
  int tid = threadIdx.x;
  int pl = tid & 15, kq = tid >> 4;   // 16 pos x 16 kq (8 kt each)
  int pos = blockIdx.x * 16 + pl;
  const f32x4* p4 = reinterpret_cast<const f32x4*>(pout) + pos;
  f32x4 s = (f32x4)0.f;
  #pragma unroll
  for (int kk = 0; kk < 8; ++kk)
    s += p4[(size_t)(kq * 8 + kk) * TOT4];
  red[pl][kq] = s;
  __syncthreads();
  if (tid < 16) {
    f32x4 tot = (f32x4)0.f;
    #pragma unroll
    for (int q = 0; q < 16; ++q) tot += red[tid][q];
    int mypos = blockIdx.x * 16 + tid;
    f32x4* r4 = reinterpret_cast<f32x4*>(res);
    f32x4 nv;
    if (ids) {
      int b = mypos >> 9, d4 = mypos & 511;
      f32x4 base = reinterpret_cast<const f32x4*>(emb)[(size_t)ids[b] * (D_ / 4) + d4];
      nv = base + tot;
    } else {
      nv = r4[mypos] + tot;
    }
    r4[mypos] = nv;
    float ps = nv[0]*nv[0] + nv[1]*nv[1] + nv[2]*nv[2] + nv[3]*nv[3];
    #pragma unroll
    for (int off = 1; off < 16; off <<= 1) ps += __shfl_xor(ps, off, 64);
    if (tid == 0) atomicAdd(&ssq_in[(mypos >> 9) * SSQS], ps);
  }
}

// ---------------- logits: wave-per-row, split-D (SL=4), FUSED final norm -----
#define SL_ 4
#define KS_ (D_ / SL_)            // 512
#define NVB16 (V_ / 16)           // 3143 (exact)
__global__ __launch_bounds__(256)
void k_logits(const float* __restrict__ res, const float* __restrict__ ssq_in,
              const float* __restrict__ nfw, const float* __restrict__ emb,
              float* __restrict__ pl) {
  __shared__ f32x4 xs[8][KS_ / 4];   // 16 KB -> 8 blocks/CU, 32 waves/CU
  int s = blockIdx.x & 3, vb = blockIdx.x >> 2;
  const f32x4* res4 = reinterpret_cast<const f32x4*>(res);
  const f32x4* nfw4 = reinterpret_cast<const f32x4*>(nfw);
  for (int i = threadIdx.x; i < 8 * (KS_ / 4); i += 256) {
    int r = i >> 7, q = i & 127;
    float scale = rsqrtf(ssq_in[r * SSQS] / (float)D_ + EPSF);
    xs[r][q] = res4[r * (D_ / 4) + s * (KS_ / 4) + q] * scale
             * nfw4[s * (KS_ / 4) + q];
  }
  __syncthreads();
  int wid = threadIdx.x >> 6, lane = threadIdx.x & 63;
  int v0 = vb * 16 + wid * 4;
  const f32x4* e4 = reinterpret_cast<const f32x4*>(emb);
  #pragma unroll
  for (int vv = 0; vv < 4; ++vv) {
    int v = v0 + vv;
    const f32x4* ep = e4 + (size_t)v * (D_ / 4) + s * (KS_ / 4);
    float acc[8] = {0,0,0,0,0,0,0,0};
    #pragma unroll
    for (int st = 0; st < KS_ / 256; ++st) {
      int c = st * 64 + lane;
      f32x4 e = __builtin_nontemporal_load(ep + c);
      #pragma unroll
      for (int r = 0; r < 8; ++r) {
        f32x4 x = xs[r][c];
        acc[r] += e[0]*x[0] + e[1]*x[1] + e[2]*x[2] + e[3]*x[3];
      }
    }
    float u = fold_reduce8(acc, lane);
    if (lane < 8) pl[((size_t)s * 8 + lane) * V_ + v] = u;
  }
}

// ---------------- logits combine: out = sum of 4 slice partials --------------
__global__ __launch_bounds__(256)
void k_logits2(const float* __restrict__ pl, float* __restrict__ out) {
  int v = blockIdx.x * 256 + threadIdx.x;
  if (v >= V_) return;
  int r = blockIdx.y;
  float t = pl[(size_t)r * V_ + v]
          + pl[((size_t)8  + r) * V_ + v]
          + pl[((size_t)16 + r) * V_ + v]
          + pl[((size_t)24 + r) * V_ + v];
  out[(size_t)r * V_ + v] = t;
}

extern "C" void kernel_launch(void* const* d_in, const int* in_sizes, int n_in,
                              void* d_out, int out_size, void* d_ws, size_t ws_size,
                              hipStream_t stream) {
  const int*   ids    = (const int*)  d_in[0];
  const float* emb    = (const float*)d_in[1];
  const float* inW    = (const float*)d_in[2];
  const float* convW  = (const float*)d_in[3];
  const float* convB  = (const float*)d_in[4];
  const float* Alog   = (const float*)d_in[5];
  const float* dtB    = (const float*)d_in[6];
  const float* Dpar   = (const float*)d_in[7];
  const float* mnw    = (const float*)d_in[8];
  const float* outW   = (const float*)d_in[9];
  const float* lnw    = (const float*)d_in[10];
  const float* nfw    = (const float*)d_in[11];
  const float* Wmc    = (const float*)d_in[12];
  const float* convS  = (const float*)d_in[13];
  const float* ssmS   = (const float*)d_in[14];
  const float* cached = (const float*)d_in[15];
  float* out = (float*)d_out;
  float* ws  = (float*)d_ws;

  float* res   = ws;            // 16384 floats
  float* zx    = ws + 16384;    // 68096
  float* xbc   = ws + 84480;    // 34816
  float* dts   = ws + 119296;   // 512
  float* dav   = ws + 119808;   // 512
  float* wmc   = ws + 120320;   // 64
  float* ssqi  = ws + 120384;   // 128 (8 used, stride 16)
  float* gpart = ws + 120512;   // 4096 (state gnorm partials)
  float* y     = ws + 124608;   // 32768
  float* pin   = ws + 157376;   // 32*8*8512 = 2179072
  float* pout  = ws + 2336448;  // 128*8*2048 = 2097152
  float* pl    = ws + 4433600;  // 4*8*50288 = 1609216 -> ends 6042816 (~24.2MB)

  for (int l = 0; l < LN; ++l) {
    if (l == 0)
      k_inproj1_first<<<288, 256, 0, stream>>>(ids, emb, lnw, inW, pin);
    else
      k_inproj1<<<288, 256, 0, stream>>>(res, ssqi, lnw + (size_t)l * D_,
                                         inW + (size_t)l * D_ * DOUT, pin);
    k_inproj2_conv<<<266, 256, 0, stream>>>(pin,
        convS + (size_t)l * B_ * CCH * K_, convW + (size_t)l * CCH * K_,
        convB + (size_t)l * CCH, Alog + l * H_, dtB + l * H_, Wmc + l * (M_ + 1),
        zx, xbc, dts, dav, wmc, ssqi);
    k_state<<<4096, 256, 0, stream>>>(xbc, zx, dts, dav, Dpar + l * H_, wmc,
        ssmS + (size_t)l * B_ * H_ * P_ * N_,
        cached + (size_t)l * B_ * M_ * H_ * P_ * N_, y, gpart);
    k_outproj1<<<256, 256, 0, stream>>>(y, zx, mnw + (size_t)l * DI, gpart,
                                        outW + (size_t)l * DI * D_, pout);
    k_outproj2<<<256, 256, 0, stream>>>(pout, res,
                                        (l == 0) ? ids : nullptr, emb, ssqi);
  }
  k_logits<<<NVB16 * SL_, 256, 0, stream>>>(res, ssqi, nfw, emb, pl);
  k_logits2<<<dim3((V_ + 255) / 256, 8), 256, 0, stream>>>(pl, out);
}

// Round 17
// 404.121 us; speedup vs baseline: 5.9449x; 1.0159x over previous
//
#include <hip/hip_runtime.h>
#include <hip/hip_bf16.h>
#include <math.h>

#define LN 4
#define B_ 8
#define D_ 2048
#define DI 4096
#define N_ 128
#define H_ 64
#define P_ 64
#define K_ 4
#define M_ 8
#define V_ 50288
#define CCH (DI + 2*N_)           // 4352
#define DOUT (2*DI + 2*N_ + H_)   // 8512
#define EPSF 1e-5f
#define KT_IN 32                  // in_proj k-tiles (k0=64)
#define KT_OUT 128                // out_proj k-tiles (k0=32)
#define SSQS 16                   // ssq_in stride (floats) -> one cache line each

typedef float f32x4 __attribute__((ext_vector_type(4)));

__device__ inline float wave_sum(float v) {
  #pragma unroll
  for (int off = 32; off > 0; off >>= 1) v += __shfl_xor(v, off, 64);
  return v;
}

// Fold-reduce 8 per-lane accumulators: lane l gets full 64-lane sum of a[l&7].
__device__ inline float fold_reduce8(const float a[8], int lane) {
  float t0[4];
  #pragma unroll
  for (int r = 0; r < 4; ++r) {
    float keep = (lane & 1) ? a[2*r+1] : a[2*r];
    float send = (lane & 1) ? a[2*r]   : a[2*r+1];
    t0[r] = keep + __shfl_xor(send, 1, 64);
  }
  float t1[2];
  #pragma unroll
  for (int r = 0; r < 2; ++r) {
    float keep = (lane & 2) ? t0[2*r+1] : t0[2*r];
    float send = (lane & 2) ? t0[2*r]   : t0[2*r+1];
    t1[r] = keep + __shfl_xor(send, 2, 64);
  }
  float keep = (lane & 4) ? t1[1] : t1[0];
  float send = (lane & 4) ? t1[0] : t1[1];
  float u = keep + __shfl_xor(send, 4, 64);
  u += __shfl_xor(u, 8, 64);
  u += __shfl_xor(u, 16, 64);
  u += __shfl_xor(u, 32, 64);
  return u;
}

// ------ in_proj stage 1, LAYER 0: embed-gather + in-block rmsnorm prologue ---
__global__ __launch_bounds__(256)
void k_inproj1_first(const int* __restrict__ ids, const float* __restrict__ emb,
                     const float* __restrict__ lnw, const float* __restrict__ W,
                     float* __restrict__ pin) {
  __shared__ float xs[8][64];
  __shared__ float sred[4][8];
  int tid = threadIdx.x, lane = tid & 63, wid = tid >> 6;
  int jt = blockIdx.x % 9, kt = blockIdx.x / 9;
  int k0 = kt * 64;
  float ssq[8];
  #pragma unroll
  for (int r = 0; r < 8; ++r) {
    const float* row = emb + (size_t)ids[r] * D_;
    f32x4 a = *reinterpret_cast<const f32x4*>(row + tid * 8);
    f32x4 c = *reinterpret_cast<const f32x4*>(row + tid * 8 + 4);
    ssq[r] = a[0]*a[0] + a[1]*a[1] + a[2]*a[2] + a[3]*a[3]
           + c[0]*c[0] + c[1]*c[1] + c[2]*c[2] + c[3]*c[3];
  }
  #pragma unroll
  for (int r = 0; r < 8; ++r) {
    float wsum = wave_sum(ssq[r]);
    if (lane == 0) sred[wid][r] = wsum;
  }
  __syncthreads();
  for (int i = tid; i < 8 * 64; i += 256) {
    int r = i >> 6, kk = i & 63;
    const float* row = emb + (size_t)ids[r] * D_;
    float tot = sred[0][r] + sred[1][r] + sred[2][r] + sred[3][r];
    float scale = rsqrtf(tot / (float)D_ + EPSF);
    xs[r][kk] = row[k0 + kk] * scale * lnw[k0 + kk];
  }
  __syncthreads();
  int j = jt * 1024 + tid * 4;
  if (j >= DOUT) return;
  f32x4 acc[8];
  #pragma unroll
  for (int r = 0; r < 8; ++r) acc[r] = (f32x4)0.f;
  const float* Wp = W + (size_t)k0 * DOUT + j;
  for (int kk = 0; kk < 64; ++kk) {
    f32x4 w4 = __builtin_nontemporal_load(
        reinterpret_cast<const f32x4*>(Wp + (size_t)kk * DOUT));
    #pragma unroll
    for (int r = 0; r < 8; ++r) acc[r] += w4 * xs[r][kk];
  }
  #pragma unroll
  for (int r = 0; r < 8; ++r)
    *reinterpret_cast<f32x4*>(&pin[((size_t)kt * 8 + r) * DOUT + j]) = acc[r];
}

// ------ in_proj stage 1, layers 1-3: 288 blocks, norm via ssq_in (stride) ----
__global__ __launch_bounds__(256)
void k_inproj1(const float* __restrict__ res, const float* __restrict__ ssq_in,
               const float* __restrict__ lnw, const float* __restrict__ W,
               float* __restrict__ pin) {
  __shared__ float xs[8][64];
  int tid = threadIdx.x;
  int jt = blockIdx.x % 9, kt = blockIdx.x / 9;
  int k0 = kt * 64;
  for (int i = tid; i < 8 * 64; i += 256) {
    int r = i >> 6, kk = i & 63;
    float scale = rsqrtf(ssq_in[r * SSQS] / (float)D_ + EPSF);
    xs[r][kk] = res[r * D_ + k0 + kk] * scale * lnw[k0 + kk];
  }
  __syncthreads();
  int j = jt * 1024 + tid * 4;
  if (j >= DOUT) return;
  f32x4 acc[8];
  #pragma unroll
  for (int r = 0; r < 8; ++r) acc[r] = (f32x4)0.f;
  const float* Wp = W + (size_t)k0 * DOUT + j;
  for (int kk = 0; kk < 64; ++kk) {
    f32x4 w4 = __builtin_nontemporal_load(
        reinterpret_cast<const f32x4*>(Wp + (size_t)kk * DOUT));
    #pragma unroll
    for (int r = 0; r < 8; ++r) acc[r] += w4 * xs[r][kk];
  }
  #pragma unroll
  for (int r = 0; r < 8; ++r)
    *reinterpret_cast<f32x4*>(&pin[((size_t)kt * 8 + r) * DOUT + j]) = acc[r];
}

// ------- in_proj stage 2: 266 blocks, 4 threads/element (8 kt-partials each),
// ------- LDS combine, fused conv+dt+softmax epilogue; block 1 zeroes ssq_in.
__global__ __launch_bounds__(256)
void k_inproj2_conv(const float* __restrict__ pin, const float* __restrict__ conv_state,
                    const float* __restrict__ conv_w, const float* __restrict__ conv_b,
                    const float* __restrict__ A_log, const float* __restrict__ dt_bias,
                    const float* __restrict__ W_mc,
                    float* __restrict__ zx, float* __restrict__ xbc,
                    float* __restrict__ dts, float* __restrict__ dav,
                    float* __restrict__ wmc, float* __restrict__ ssq_in) {
  __shared__ f32x4 red[4][64];
  const int TOT4 = B_ * DOUT / 4;   // 17024 = 266 * 64
  int tid = threadIdx.x;
  if (blockIdx.x == 1 && tid < 8) ssq_in[tid * SSQS] = 0.f;
  int el = tid & 63, kq = tid >> 6;
  int e = blockIdx.x * 64 + el;
  f32x4 s = (f32x4)0.f;
  const f32x4* p4 = reinterpret_cast<const f32x4*>(pin) + e;
  #pragma unroll
  for (int kk = 0; kk < 8; ++kk)
    s += p4[(size_t)(kq * 8 + kk) * TOT4];
  red[kq][el] = s;
  __syncthreads();
  if (tid >= 64) return;
  s = red[0][tid] + red[1][tid] + red[2][tid] + red[3][tid];
  reinterpret_cast<f32x4*>(zx)[e] = s;
  int c4 = e * 4;
  int b = c4 / DOUT;
  int c = c4 - b * DOUT;
  #pragma unroll
  for (int q = 0; q < 4; ++q) {
    int ce = c + q;
    if (ce >= DI && ce < DI + CCH) {
      int cc = ce - DI;
      f32x4 cs4 = *reinterpret_cast<const f32x4*>(conv_state + ((size_t)b * CCH + cc) * K_);
      f32x4 cw4 = *reinterpret_cast<const f32x4*>(conv_w + (size_t)cc * K_);
      float v = cs4[1] * cw4[0] + cs4[2] * cw4[1] + cs4[3] * cw4[2]
              + s[q] * cw4[3] + conv_b[cc];
      xbc[b * CCH + cc] = v / (1.f + expf(-v));   // silu
    } else if (ce >= DI + CCH) {
      int h = ce - DI - CCH;
      float x = s[q] + dt_bias[h];
      float sp = (x > 20.f) ? x : log1pf(expf(x));  // softplus
      dts[b * 64 + h] = sp;
      dav[b * 64 + h] = expf(-expf(A_log[h]) * sp);
    }
  }
  if (blockIdx.x == 0 && tid == 0) {
    float mx = -1e30f;
    for (int i = 0; i < M_ + 1; ++i) mx = fmaxf(mx, W_mc[i]);
    float e2[M_ + 1], sum = 0.f;
    for (int i = 0; i < M_ + 1; ++i) { e2[i] = expf(W_mc[i] - mx); sum += e2[i]; }
    for (int i = 0; i < M_ + 1; ++i) wmc[i] = e2[i] / sum;
  }
}

// -------- state update + MC fuse + y; 1024-thread blocks (16 waves) covering
// -------- 32 consecutive p of one (b,h): 16KB contiguous per m-stream.
// -------- gnorm partial via plain store to gpart[bid] (1024 distinct addrs).
__global__ __launch_bounds__(1024)
void k_state(const float* __restrict__ xbc, const float* __restrict__ zx,
             const float* __restrict__ dts, const float* __restrict__ dav,
             const float* __restrict__ Dp_, const float* __restrict__ wmc,
             const float* __restrict__ ssm, const float* __restrict__ cached,
             float* __restrict__ y, float* __restrict__ gpart) {
  __shared__ float gred[32];
  int tid = threadIdx.x;
  int lane = tid & 63, widx = tid >> 6;          // 16 waves
  int bid = blockIdx.x;                          // 1024 blocks
  int b  = bid >> 7;                             // 128 blocks per b
  int h  = (bid >> 1) & 63;
  int ph = bid & 1;
  int hf = lane >> 5, il = lane & 31;
  int p = ph * 32 + widx * 2 + hf;
  float xv  = xbc[b * CCH + h * 64 + p];
  float dtv = dts[b * 64 + h];
  float da  = dav[b * 64 + h];
  float w8  = wmc[8];
  const f32x4* xb4 = reinterpret_cast<const f32x4*>(xbc);
  f32x4 B4 = xb4[b * (CCH / 4) + DI / 4 + il];
  f32x4 C4 = xb4[b * (CCH / 4) + DI / 4 + N_ / 4 + il];
  const f32x4* sp4 = reinterpret_cast<const f32x4*>(ssm) +
                     ((size_t)((b * H_ + h) * P_ + p)) * (N_ / 4) + il;
  const f32x4* cp4 = reinterpret_cast<const f32x4*>(cached) +
                     ((size_t)(((b * M_) * H_ + h) * P_ + p)) * (N_ / 4) + il;
  f32x4 s4 = __builtin_nontemporal_load(sp4);
  f32x4 f4 = (s4 * da + B4 * (dtv * xv)) * w8;
  #pragma unroll
  for (int m = 0; m < 8; ++m) {
    f32x4 c4 = __builtin_nontemporal_load(cp4 + (size_t)m * (H_ * P_ * N_ / 4));
    f4 += c4 * wmc[m];
  }
  f4 *= C4;
  float acc = f4[0] + f4[1] + f4[2] + f4[3];
  #pragma unroll
  for (int off = 1; off < 32; off <<= 1) acc += __shfl_xor(acc, off, 64);
  if (il == 0) {
    float yv = acc + Dp_[h] * xv;
    int d = h * 64 + p;
    y[b * DI + d] = yv;
    float z = zx[b * DOUT + d];
    float v = yv * (z / (1.f + expf(-z)));
    gred[widx * 2 + hf] = v * v;
  }
  __syncthreads();
  if (tid == 0) {
    float g = 0.f;
    #pragma unroll
    for (int i = 0; i < 32; ++i) g += gred[i];
    gpart[bid] = g;
  }
}

// ------ out_proj stage 1 with gated-norm: reduces gpart (adds-only, L2-hot),
// ------ stages y*silu(z)*rsqrt(ssq/DI+eps)*mnw (1 expf/thread) ---------------
__global__ __launch_bounds__(256)
void k_outproj1(const float* __restrict__ y, const float* __restrict__ zx,
                const float* __restrict__ mnw, const float* __restrict__ gpart,
                const float* __restrict__ W, float* __restrict__ pout) {
  __shared__ float xs[8][32];
  __shared__ float sred[8];
  int tid = threadIdx.x;
  {
    // reduce gpart[r*128 .. +128) for row r = tid>>5 (32 threads x 1 f32x4)
    int r = tid >> 5, t32 = tid & 31;
    f32x4 a = reinterpret_cast<const f32x4*>(gpart)[r * 32 + t32];
    float s = a[0] + a[1] + a[2] + a[3];
    #pragma unroll
    for (int off = 1; off < 32; off <<= 1) s += __shfl_xor(s, off, 64);
    if (t32 == 0) sred[r] = s;
  }
  __syncthreads();
  int jt = blockIdx.x & 1, kt = blockIdx.x >> 1;
  int k0 = kt * 32;
  {
    int r = tid >> 5, kk = tid & 31;
    float scale = rsqrtf(sred[r] / (float)DI + EPSF);
    float z = zx[r * DOUT + k0 + kk];
    float g = z / (1.f + expf(-z));
    xs[r][kk] = y[r * DI + k0 + kk] * g * scale * mnw[k0 + kk];
  }
  __syncthreads();
  int j = jt * 1024 + tid * 4;
  f32x4 acc[8];
  #pragma unroll
  for (int r = 0; r < 8; ++r) acc[r] = (f32x4)0.f;
  const float* Wp = W + (size_t)k0 * D_ + j;
  for (int kk = 0; kk < 32; ++kk) {
    f32x4 w4 = __builtin_nontemporal_load(
        reinterpret_cast<const f32x4*>(Wp + (size_t)kk * D_));
    #pragma unroll
    for (int r = 0; r < 8; ++r) acc[r] += w4 * xs[r][kk];
  }
  #pragma unroll
  for (int r = 0; r < 8; ++r)
    *reinterpret_cast<f32x4*>(&pout[((size_t)kt * 8 + r) * D_ + j]) = acc[r];
}

// ------- out_proj stage 2: 256 blocks (full chip), 16 pos x 16 kq threads,
// ------- LDS combine; res update + next-norm ssq_in accumulation.
__global__ __launch_bounds__(256)
void k_outproj2(const float* __restrict__ pout, float* __restrict__ res,
                const int* __restrict__ ids, const float* __restrict__ emb,
                float* __restrict__ ssq_in) {
  __shared__ f32x4 red[16][16];
  const int TOT4 = B_ * D_ / 4;   // 4096
  int tid = threadIdx.x;
  int pl = tid & 15, kq = tid >> 4;   // 16 pos x 16 kq (8 kt each)
  int pos = blockIdx.x * 16 + pl;
  const f32x4* p4 = reinterpret_cast<const f32x4*>(pout) + pos;
  f32x4 s = (f32x4)0.f;
  #pragma unroll
  for (int kk = 0; kk < 8; ++kk)
    s += p4[(size_t)(kq * 8 + kk) * TOT4];
  red[pl][kq] = s;
  __syncthreads();
  if (tid < 16) {
    f32x4 tot = (f32x4)0.f;
    #pragma unroll
    for (int q = 0; q < 16; ++q) tot += red[tid][q];
    int mypos = blockIdx.x * 16 + tid;
    f32x4* r4 = reinterpret_cast<f32x4*>(res);
    f32x4 nv;
    if (ids) {
      int b = mypos >> 9, d4 = mypos & 511;
      f32x4 base = reinterpret_cast<const f32x4*>(emb)[(size_t)ids[b] * (D_ / 4) + d4];
      nv = base + tot;
    } else {
      nv = r4[mypos] + tot;
    }
    r4[mypos] = nv;
    float ps = nv[0]*nv[0] + nv[1]*nv[1] + nv[2]*nv[2] + nv[3]*nv[3];
    #pragma unroll
    for (int off = 1; off < 16; off <<= 1) ps += __shfl_xor(ps, off, 64);
    if (tid == 0) atomicAdd(&ssq_in[(mypos >> 9) * SSQS], ps);
  }
}

// ---------------- logits: wave-per-row, split-D (SL=4), FUSED final norm -----
#define SL_ 4
#define KS_ (D_ / SL_)            // 512
#define NVB16 (V_ / 16)           // 3143 (exact)
__global__ __launch_bounds__(256)
void k_logits(const float* __restrict__ res, const float* __restrict__ ssq_in,
              const float* __restrict__ nfw, const float* __restrict__ emb,
              float* __restrict__ pl) {
  __shared__ f32x4 xs[8][KS_ / 4];   // 16 KB -> 8 blocks/CU, 32 waves/CU
  int s = blockIdx.x & 3, vb = blockIdx.x >> 2;
  const f32x4* res4 = reinterpret_cast<const f32x4*>(res);
  const f32x4* nfw4 = reinterpret_cast<const f32x4*>(nfw);
  for (int i = threadIdx.x; i < 8 * (KS_ / 4); i += 256) {
    int r = i >> 7, q = i & 127;
    float scale = rsqrtf(ssq_in[r * SSQS] / (float)D_ + EPSF);
    xs[r][q] = res4[r * (D_ / 4) + s * (KS_ / 4) + q] * scale
             * nfw4[s * (KS_ / 4) + q];
  }
  __syncthreads();
  int wid = threadIdx.x >> 6, lane = threadIdx.x & 63;
  int v0 = vb * 16 + wid * 4;
  const f32x4* e4 = reinterpret_cast<const f32x4*>(emb);
  #pragma unroll
  for (int vv = 0; vv < 4; ++vv) {
    int v = v0 + vv;
    const f32x4* ep = e4 + (size_t)v * (D_ / 4) + s * (KS_ / 4);
    float acc[8] = {0,0,0,0,0,0,0,0};
    #pragma unroll
    for (int st = 0; st < KS_ / 256; ++st) {
      int c = st * 64 + lane;
      f32x4 e = __builtin_nontemporal_load(ep + c);
      #pragma unroll
      for (int r = 0; r < 8; ++r) {
        f32x4 x = xs[r][c];
        acc[r] += e[0]*x[0] + e[1]*x[1] + e[2]*x[2] + e[3]*x[3];
      }
    }
    float u = fold_reduce8(acc, lane);
    if (lane < 8) pl[((size_t)s * 8 + lane) * V_ + v] = u;
  }
}

// ---------------- logits combine: out = sum of 4 slice partials --------------
__global__ __launch_bounds__(256)
void k_logits2(const float* __restrict__ pl, float* __restrict__ out) {
  int v = blockIdx.x * 256 + threadIdx.x;
  if (v >= V_) return;
  int r = blockIdx.y;
  float t = pl[(size_t)r * V_ + v]
          + pl[((size_t)8  + r) * V_ + v]
          + pl[((size_t)16 + r) * V_ + v]
          + pl[((size_t)24 + r) * V_ + v];
  out[(size_t)r * V_ + v] = t;
}

extern "C" void kernel_launch(void* const* d_in, const int* in_sizes, int n_in,
                              void* d_out, int out_size, void* d_ws, size_t ws_size,
                              hipStream_t stream) {
  const int*   ids    = (const int*)  d_in[0];
  const float* emb    = (const float*)d_in[1];
  const float* inW    = (const float*)d_in[2];
  const float* convW  = (const float*)d_in[3];
  const float* convB  = (const float*)d_in[4];
  const float* Alog   = (const float*)d_in[5];
  const float* dtB    = (const float*)d_in[6];
  const float* Dpar   = (const float*)d_in[7];
  const float* mnw    = (const float*)d_in[8];
  const float* outW   = (const float*)d_in[9];
  const float* lnw    = (const float*)d_in[10];
  const float* nfw    = (const float*)d_in[11];
  const float* Wmc    = (const float*)d_in[12];
  const float* convS  = (const float*)d_in[13];
  const float* ssmS   = (const float*)d_in[14];
  const float* cached = (const float*)d_in[15];
  float* out = (float*)d_out;
  float* ws  = (float*)d_ws;

  float* res   = ws;            // 16384 floats
  float* zx    = ws + 16384;    // 68096
  float* xbc   = ws + 84480;    // 34816
  float* dts   = ws + 119296;   // 512
  float* dav   = ws + 119808;   // 512
  float* wmc   = ws + 120320;   // 64
  float* ssqi  = ws + 120384;   // 128 (8 used, stride 16)
  float* gpart = ws + 120512;   // 1024 (state gnorm partials)
  float* y     = ws + 121536;   // 32768
  float* pin   = ws + 154304;   // 32*8*8512 = 2179072
  float* pout  = ws + 2333376;  // 128*8*2048 = 2097152
  float* pl    = ws + 4430528;  // 4*8*50288 = 1609216 -> ends 6039744 (~24.2MB)

  for (int l = 0; l < LN; ++l) {
    if (l == 0)
      k_inproj1_first<<<288, 256, 0, stream>>>(ids, emb, lnw, inW, pin);
    else
      k_inproj1<<<288, 256, 0, stream>>>(res, ssqi, lnw + (size_t)l * D_,
                                         inW + (size_t)l * D_ * DOUT, pin);
    k_inproj2_conv<<<266, 256, 0, stream>>>(pin,
        convS + (size_t)l * B_ * CCH * K_, convW + (size_t)l * CCH * K_,
        convB + (size_t)l * CCH, Alog + l * H_, dtB + l * H_, Wmc + l * (M_ + 1),
        zx, xbc, dts, dav, wmc, ssqi);
    k_state<<<1024, 1024, 0, stream>>>(xbc, zx, dts, dav, Dpar + l * H_, wmc,
        ssmS + (size_t)l * B_ * H_ * P_ * N_,
        cached + (size_t)l * B_ * M_ * H_ * P_ * N_, y, gpart);
    k_outproj1<<<256, 256, 0, stream>>>(y, zx, mnw + (size_t)l * DI, gpart,
                                        outW + (size_t)l * DI * D_, pout);
    k_outproj2<<<256, 256, 0, stream>>>(pout, res,
                                        (l == 0) ? ids : nullptr, emb, ssqi);
  }
  k_logits<<<NVB16 * SL_, 256, 0, stream>>>(res, ssqi, nfw, emb, pl);
  k_logits2<<<dim3((V_ + 255) / 256, 8), 256, 0, stream>>>(pl, out);
}